// Round 2
// baseline (256.705 us; speedup 1.0000x reference)
//
#include <hip/hip_runtime.h>
#include <hip/hip_bf16.h>

using bf16 = __hip_bfloat16;

typedef __bf16 bf16x8 __attribute__((ext_vector_type(8)));
typedef __bf16 bf16x4v __attribute__((ext_vector_type(4)));
typedef __bf16 bf16x2v __attribute__((ext_vector_type(2)));
typedef float  float4v __attribute__((ext_vector_type(4)));

#define MFMA16x16x32(a, b, c) __builtin_amdgcn_mfma_f32_16x16x32_bf16((a), (b), (c), 0, 0, 0)

#if __has_builtin(__builtin_amdgcn_exp2f)
#define EXP2F(x) __builtin_amdgcn_exp2f(x)
#else
#define EXP2F(x) exp2f(x)
#endif

#define T_SEQ 2048
#define NHEAD 16
#define CDIM  1024
#define HD3   3072

// async global->LDS, 16B per lane. LDS dest must be wave-uniform base + lane*16.
__device__ __forceinline__ void async_copy16(const void* g, void* l) {
    __builtin_amdgcn_global_load_lds(
        (__attribute__((address_space(1))) unsigned int*)g,
        (__attribute__((address_space(3))) unsigned int*)l,
        16, 0, 0);
}

// native f32 atomic add (device scope by default on gfx950; "unsafe" = fp
// denorm semantics, fine for partial-sum accumulation).
__device__ __forceinline__ void atomAddF32(float* p, float v) {
    unsafeAtomicAdd(p, v);
}

// ---------------------------------------------------------------------------
// Runtime dtype probe: flag=1 -> fp32 inputs, 0 -> bf16.
// ---------------------------------------------------------------------------
__global__ __launch_bounds__(256) void detect_dtype_kernel(
    const unsigned short* __restrict__ xs, int* __restrict__ flag)
{
    __shared__ int red[256];
    int cnt = 0;
    for (int i = threadIdx.x; i < 16384; i += 256) {
        const unsigned short u = xs[i];
        const int e = (u >> 7) & 0xFF;
        if (e == 0xFF || (e != 0 && e < 0x60)) cnt++;
    }
    red[threadIdx.x] = cnt;
    __syncthreads();
    for (int s = 128; s > 0; s >>= 1) {
        if (threadIdx.x < s) red[threadIdx.x] += red[threadIdx.x + s];
        __syncthreads();
    }
    if (threadIdx.x == 0) flag[0] = (red[0] > 100) ? 1 : 0;
}

__global__ __launch_bounds__(256) void convert_f32_kernel(
    const float* __restrict__ x, const float* __restrict__ wa,
    const float* __restrict__ wp,
    bf16* __restrict__ xb, bf16* __restrict__ wab, bf16* __restrict__ wpb,
    const int* __restrict__ flag)
{
    if (flag[0] == 0) return;
    const int stride = gridDim.x * 256;
    for (int i = blockIdx.x * 256 + threadIdx.x; i < 8388608; i += stride) {
        if (i < 4194304)      xb[i] = __float2bfloat16(x[i]);
        else if (i < 7340032) wab[i - 4194304] = __float2bfloat16(wa[i - 4194304]);
        else                  wpb[i - 7340032] = __float2bfloat16(wp[i - 7340032]);
    }
}

// Zero the attention partial buffers (poS + plv, contiguous 8,650,752 B).
// Launched after gemm1 (the region overlays dead xb/wab), before attn_split.
__global__ __launch_bounds__(256) void zero_partials(float4v* __restrict__ p)
{
    const int stride = gridDim.x * 256;
    const float4v z = {0.f, 0.f, 0.f, 0.f};
    for (int i = blockIdx.x * 256 + threadIdx.x; i < 540672; i += stride)
        p[i] = z;
}

// ---------------------------------------------------------------------------
// NT GEMM, BK=64, XOR-swizzled async staging. C[m,n]=sum_k A[m,k]B[n,k]+bias.
// scale_q: multiply (acc+bias) by 0.125*log2e for cols < 1024 (q-columns).
// ---------------------------------------------------------------------------
__global__ __launch_bounds__(256) void gemm_nt_lds(
    const void* __restrict__ Araw, const bf16* __restrict__ Aconv,
    const void* __restrict__ Braw, const bf16* __restrict__ Bconv,
    const void* __restrict__ biasraw, void* __restrict__ Cv,
    int M, int N, int K, const int* __restrict__ flag, int is_final, int scale_q)
{
    const bool f32 = (flag[0] != 0);
    const bf16* A = f32 ? Aconv : (const bf16*)Araw;
    const bf16* B = f32 ? Bconv : (const bf16*)Braw;

    __shared__ bf16 As[128 * 64];
    __shared__ bf16 Bs[128 * 64];

    const int tid  = threadIdx.x;
    const int lane = tid & 63;
    const int wave = tid >> 6;
    const int wm = wave & 1, wn = wave >> 1;
    const int c = lane & 15, g = lane >> 4;

    const int bm = blockIdx.x * 128;
    const int bn = blockIdx.y * 128;

    const int srow = tid >> 3;
    const int slc  = ((tid & 7) ^ (srow & 7)) * 8;
    const bf16* gA = A + (size_t)(bm + srow) * K + slc;
    const bf16* gB = B + (size_t)(bn + srow) * K + slc;

    float4v acc[4][4] = {};

    for (int k0 = 0; k0 < K; k0 += 64) {
        __syncthreads();
#pragma unroll
        for (int q = 0; q < 4; ++q) {
            async_copy16(gA + k0 + (size_t)(q * 32) * K, As + q * 2048 + tid * 8);
            async_copy16(gB + k0 + (size_t)(q * 32) * K, Bs + q * 2048 + tid * 8);
        }
        __syncthreads();

#pragma unroll
        for (int kk = 0; kk < 2; ++kk) {
            bf16x8 af[4], bfr[4];
#pragma unroll
            for (int i = 0; i < 4; ++i) {
                af[i]  = *(const bf16x8*)&As[(wm * 64 + i * 16 + c) * 64 +
                                             (((kk * 4 + g) ^ (c & 7)) * 8)];
                bfr[i] = *(const bf16x8*)&Bs[(wn * 64 + i * 16 + c) * 64 +
                                             (((kk * 4 + g) ^ (c & 7)) * 8)];
            }
#pragma unroll
            for (int i = 0; i < 4; ++i)
#pragma unroll
                for (int j = 0; j < 4; ++j)
                    acc[i][j] = MFMA16x16x32(af[i], bfr[j], acc[i][j]);
        }
    }

    const bool f32o = is_final && f32;
    bf16*  Cb = (bf16*)Cv;
    float* Cf = (float*)Cv;

#pragma unroll
    for (int i = 0; i < 4; ++i) {
        const int row = bm + wm * 64 + i * 16 + g * 4;
#pragma unroll
        for (int j = 0; j < 4; ++j) {
            const int col = bn + wn * 64 + j * 16 + c;
            const float bv = f32 ? ((const float*)biasraw)[col]
                                 : __bfloat162float(((const bf16*)biasraw)[col]);
            const float sc = (scale_q && col < 1024) ? 0.18033688f : 1.0f;
            if (f32o) {
#pragma unroll
                for (int t = 0; t < 4; ++t)
                    Cf[(size_t)(row + t) * N + col] = (acc[i][j][t] + bv) * sc;
            } else {
#pragma unroll
                for (int t = 0; t < 4; ++t)
                    Cb[(size_t)(row + t) * N + col] =
                        __float2bfloat16((acc[i][j][t] + bv) * sc);
            }
        }
    }
}

// ---------------------------------------------------------------------------
// Flash attention v6b: exact uniform work partition via key-splitting.
// Work in 64-key units: total = 32bh * sum_j 2(j+1) = 8704 = 512 blocks * 17.
// Pair pj (heavy H=15-pj, light L=pj): role A = H keys [0,1088);
// role B = H keys [1088, (32-2pj)*64) then all of L. Softmax is un-maxed
// exp2, so disjoint-key partials (o,l) merge by pure addition: both roles
// unsafeAtomicAdd into a zeroed poS buffer; merge kernel normalizes.
// KT=64 double-buffered (LDS 32KB => 2 blocks/CU sustained, uniform work).
// ---------------------------------------------------------------------------
__device__ __forceinline__ void attn_segment(
    const bf16* __restrict__ kgbase, const bf16* __restrict__ vgbase,
    __bf16* __restrict__ Ks, __bf16* __restrict__ Vt,   // each [2][64*64]
    int u0, int uN, int qw,
    const bf16x8 qf[2][2], float4v o[2][4], float4v ol[2], int tid)
{
    const int lane = tid & 63;
    const int c = lane & 15, g = lane >> 4;
    const int krow = tid >> 3;                       // K: key row 0..31 (+q*32)
    const int klc  = ((tid & 7) ^ (krow & 7)) * 8;   // K: swizzled source col
    const int kq   = tid & 31;                       // V: key pair id (keys 2kq,2kq+1)
    const int dgv  = tid >> 5;                       // V: dim chunk 0..7
    // key<->kappa permutation required by the PV fragment pairing:
    // key = (cc>>2)*32 + (jj>>2)*16 + (cc&3)*4 + (jj&3), kappa = cc*8+jj.
    const int vcc  = ((kq >> 4) << 2) | ((kq >> 1) & 3);
    const int vjjb = (((kq >> 3) & 1) << 2) | ((kq & 1) << 1);

    bf16x8 ones;
#pragma unroll
    for (int ii = 0; ii < 8; ++ii) ones[ii] = (__bf16)1.0f;

    // prologue: stage unit u0 into buffer 0
#pragma unroll
    for (int q = 0; q < 2; ++q)
        async_copy16(kgbase + (size_t)(u0 * 64 + q * 32 + krow) * HD3 + klc,
                     Ks + q * 2048 + tid * 8);
    {
        bf16x8 vr[2];
#pragma unroll
        for (int r = 0; r < 2; ++r)
            vr[r] = *(const bf16x8*)(vgbase + (size_t)(u0 * 64 + kq * 2 + r) * HD3 + dgv * 8);
#pragma unroll
        for (int jj = 0; jj < 8; ++jj) {
            const int d = dgv * 8 + jj;
            bf16x2v pk; pk[0] = vr[0][jj]; pk[1] = vr[1][jj];
            *(bf16x2v*)&Vt[d * 64 + ((vcc ^ (d & 7)) << 3) + vjjb] = pk;
        }
    }
    __syncthreads();

    int b = 0;
    for (int u = u0; u < uN; ++u, b ^= 1) {
        const int kt = u * 64;
        const bool more = (u + 1 < uN);
        bf16x8 vr[2];
        if (more) {
#pragma unroll
            for (int q = 0; q < 2; ++q)
                async_copy16(kgbase + (size_t)(kt + 64 + q * 32 + krow) * HD3 + klc,
                             Ks + (b ^ 1) * 4096 + q * 2048 + tid * 8);
#pragma unroll
            for (int r = 0; r < 2; ++r)
                vr[r] = *(const bf16x8*)(vgbase + (size_t)(kt + 64 + kq * 2 + r) * HD3 + dgv * 8);
        }

        if (kt <= qw + 31) {                // wave-uniform causal skip
            const __bf16* Kb = Ks + b * 4096;
            const __bf16* Vb = Vt + b * 4096;

            // ---- S^T = K Q^T over 64 keys ----
            float4v sacc[2][4] = {};
            __builtin_amdgcn_s_setprio(1);
#pragma unroll
            for (int jb = 0; jb < 4; ++jb) {
                const int key = jb * 16 + c;
                bf16x8 a0 = *(const bf16x8*)&Kb[key * 64 + ((g ^ (c & 7)) * 8)];
                bf16x8 a1 = *(const bf16x8*)&Kb[key * 64 + (((4 + g) ^ (c & 7)) * 8)];
#pragma unroll
                for (int a = 0; a < 2; ++a) {
                    sacc[a][jb] = MFMA16x16x32(a0, qf[a][0], sacc[a][jb]);
                    sacc[a][jb] = MFMA16x16x32(a1, qf[a][1], sacc[a][jb]);
                }
            }
            __builtin_amdgcn_s_setprio(0);

            // ---- mask + exp2 + pack P (registers only) ----
            bf16x8 pf[2][2];
#pragma unroll
            for (int a = 0; a < 2; ++a) {
                const int qmin = qw + a * 16;
                if (kt + 63 > qmin) {
                    const int query = qmin + c;
#pragma unroll
                    for (int jb = 0; jb < 4; ++jb) {
                        const int kb = kt + jb * 16 + g * 4;
#pragma unroll
                        for (int t = 0; t < 4; ++t)
                            if (kb + t > query) sacc[a][jb][t] = -1e30f;
                    }
                }
#pragma unroll
                for (int jb = 0; jb < 4; ++jb)
#pragma unroll
                    for (int t = 0; t < 4; ++t)
                        sacc[a][jb][t] = EXP2F(sacc[a][jb][t]);
#pragma unroll
                for (int lkf = 0; lkf < 2; ++lkf) {
                    bf16x8 pk;
#pragma unroll
                    for (int jj = 0; jj < 8; ++jj)
                        pk[jj] = (__bf16)sacc[a][lkf * 2 + (jj >> 2)][jj & 3];
                    pf[a][lkf] = pk;
                }
            }

            // ---- O^T += V^T P ; lsum += 1^T P ----
            __builtin_amdgcn_s_setprio(1);
#pragma unroll
            for (int lkf = 0; lkf < 2; ++lkf) {
                ol[0] = MFMA16x16x32(ones, pf[0][lkf], ol[0]);
                ol[1] = MFMA16x16x32(ones, pf[1][lkf], ol[1]);
#pragma unroll
                for (int dn = 0; dn < 4; ++dn) {
                    const int d = dn * 16 + c;
                    bf16x8 vf = *(const bf16x8*)
                        &Vb[d * 64 + (((lkf * 4 + g) ^ (d & 7)) << 3)];
                    o[0][dn] = MFMA16x16x32(vf, pf[0][lkf], o[0][dn]);
                    o[1][dn] = MFMA16x16x32(vf, pf[1][lkf], o[1][dn]);
                }
            }
            __builtin_amdgcn_s_setprio(0);
        }

        if (more) {
            __bf16* Vn = Vt + (b ^ 1) * 4096;
#pragma unroll
            for (int jj = 0; jj < 8; ++jj) {
                const int d = dgv * 8 + jj;
                bf16x2v pk; pk[0] = vr[0][jj]; pk[1] = vr[1][jj];
                *(bf16x2v*)&Vn[d * 64 + ((vcc ^ (d & 7)) << 3) + vjjb] = pk;
            }
        }
        __syncthreads();
    }
}

__global__ __launch_bounds__(256, 2) void attn_split(
    const bf16* __restrict__ qkv, bf16* __restrict__ y,
    float* __restrict__ poS, float* __restrict__ plv)
{
    __shared__ __bf16 Ks[2 * 64 * 64];
    __shared__ __bf16 Vt[2 * 64 * 64];

    const int tid  = threadIdx.x;
    const int lane = tid & 63;
    const int w    = tid >> 6;
    const int c    = lane & 15;
    const int g    = lane >> 4;

    // XCD-aware decode: all blocks with bh === xcd (mod 8) share an XCD,
    // so the 4 bh per XCD stay L2-resident. Bijective over 512.
    const int jid  = blockIdx.x;
    const int xcd  = jid & 7;
    const int rank = jid >> 3;
    const int bh   = ((rank & 3) << 3) | xcd;   // 0..31
    const int pr   = rank >> 2;                 // 0..15
    const int pj   = pr >> 1;                   // pair 0..7
    const int role = pr & 1;                    // 0=A, 1=B

    const int bb = bh >> 4, h = bh & 15;
    const size_t base = (size_t)bb * T_SEQ * HD3 + (size_t)h * 64;
    const bf16* kgbase = qkv + base + 1024;
    const bf16* vgbase = qkv + base + 2048;

    const int Hq = 15 - pj;
    const int s  = bh * 8 + pj;                 // heavy-tile merge slot

    // ---- heavy q-tile segment (A: units [0,17); B: [17, 32-2pj)) ----
    {
        const int qw = Hq * 128 + w * 32;
        bf16x8 qf[2][2];
#pragma unroll
        for (int a = 0; a < 2; ++a)
#pragma unroll
            for (int k2 = 0; k2 < 2; ++k2)
                qf[a][k2] = *(const bf16x8*)(qkv + base
                    + (size_t)(qw + a * 16 + c) * HD3 + k2 * 32 + g * 8);

        float4v o[2][4] = {};
        float4v ol[2]   = {};
        const int u0 = role ? 17 : 0;
        const int uN = role ? (32 - 2 * pj) : 17;
        attn_segment(kgbase, vgbase, Ks, Vt, u0, uN, qw, qf, o, ol, tid);

        // accumulate f32 partial (o, l): atomics onto zeroed poS (both roles)
        float* po = poS + (size_t)s * 8192;
        float* pl = plv + (size_t)(s * 2 + role) * 128;
#pragma unroll
        for (int a = 0; a < 2; ++a) {
            const int qr = w * 32 + a * 16 + c;
#pragma unroll
            for (int dn = 0; dn < 4; ++dn)
#pragma unroll
                for (int t = 0; t < 4; ++t)
                    atomAddF32(&po[(size_t)qr * 64 + dn * 16 + g * 4 + t],
                               o[a][dn][t]);
            if (g == 0) pl[qr] = ol[a].x;
        }
    }

    // ---- light q-tile (role B only): units [0, 2pj+2), finalized here ----
    if (role) {
        const int qw = pj * 128 + w * 32;
        bf16x8 qf[2][2];
#pragma unroll
        for (int a = 0; a < 2; ++a)
#pragma unroll
            for (int k2 = 0; k2 < 2; ++k2)
                qf[a][k2] = *(const bf16x8*)(qkv + base
                    + (size_t)(qw + a * 16 + c) * HD3 + k2 * 32 + g * 8);

        float4v o[2][4] = {};
        float4v ol[2]   = {};
        attn_segment(kgbase, vgbase, Ks, Vt, 0, 2 * pj + 2, qw, qf, o, ol, tid);

#pragma unroll
        for (int a = 0; a < 2; ++a) {
            const float linv = 1.f / ol[a].x;
            const int q = qw + a * 16 + c;
            const size_t yb = ((size_t)bb * T_SEQ + q) * CDIM + h * 64;
#pragma unroll
            for (int dn = 0; dn < 4; ++dn) {
                bf16x4v ov;
#pragma unroll
                for (int t = 0; t < 4; ++t)
                    ov[t] = (__bf16)(o[a][dn][t] * linv);
                *(bf16x4v*)&y[yb + dn * 16 + g * 4] = ov;
            }
        }
    }
}

// Normalize each heavy q-tile: o = poS (sum of both roles), l = lA+lB.
__global__ __launch_bounds__(256) void attn_merge(
    const float* __restrict__ poS, const float* __restrict__ plv,
    bf16* __restrict__ y)
{
    const int s  = blockIdx.x;          // 0..255
    const int bh = s >> 3, pj = s & 7;
    const int Hq = 15 - pj;
    const int bb = bh >> 4, h = bh & 15;

    const float4v* A  = (const float4v*)(poS + (size_t)s * 8192);
    const float* la = plv + (size_t)(s * 2) * 128;
    const float* lb = la + 128;

    for (int idx = threadIdx.x; idx < 2048; idx += 256) {
        const int row = idx >> 4;           // 16 float4 per 64-dim row
        const int d0  = (idx & 15) * 4;
        const float linv = 1.f / (la[row] + lb[row]);
        float4v v = A[idx];
        bf16x4v ov;
#pragma unroll
        for (int t = 0; t < 4; ++t) ov[t] = (__bf16)(v[t] * linv);
        const int q = Hq * 128 + row;
        *(bf16x4v*)&y[((size_t)bb * T_SEQ + q) * CDIM + h * 64 + d0] = ov;
    }
}

// ---------------------------------------------------------------------------
extern "C" void kernel_launch(void* const* d_in, const int* in_sizes, int n_in,
                              void* d_out, int out_size, void* d_ws, size_t ws_size,
                              hipStream_t stream)
{
    const int M = 4096;   // B*T
    char* ws = (char*)d_ws;

    // Footprint identical to the proven baseline: max offset 50,331,904 B.
    int*  flag = (int*)ws;                        // 256 B
    bf16* xb   = (bf16*)(ws + 256);               // 8 MB   (dead after gemm1)
    bf16* wab  = (bf16*)(ws + 8388864);           // 6 MB   (dead after gemm1)
    bf16* wpb  = (bf16*)(ws + 14680320);          // 2 MB
    bf16* qkv  = (bf16*)(ws + 16777472);          // 25.2 MB
    bf16* yb   = (bf16*)(ws + 41943296);          // 8 MB -> end 50,331,904
    // attn partials overlay the dead xb/wab region (zeroed after gemm1):
    float* poS = (float*)(ws + 256);              // 8.39 MB (overlays xb)
    float* plv = (float*)(ws + 8388864);          // 256 KB  (overlays wab head)

    detect_dtype_kernel<<<1, 256, 0, stream>>>((const unsigned short*)d_in[0], flag);

    convert_f32_kernel<<<512, 256, 0, stream>>>(
        (const float*)d_in[0], (const float*)d_in[1], (const float*)d_in[3],
        xb, wab, wpb, flag);

    {   // qkv = x @ w_attn^T + b_attn  (q columns pre-scaled)
        dim3 grid(M / 128, 3072 / 128);
        gemm_nt_lds<<<grid, 256, 0, stream>>>(d_in[0], xb, d_in[1], wab,
                                              d_in[2], qkv, M, 3072, 1024, flag, 0, 1);
    }

    // zero partial buffers (xb/wab now dead; stream-ordered before atomics)
    zero_partials<<<512, 256, 0, stream>>>((float4v*)(ws + 256));

    {   // flash attention: uniform 17-unit blocks + atomic key-split merge
        attn_split<<<512, 256, 0, stream>>>(qkv, yb, poS, plv);
        attn_merge<<<256, 256, 0, stream>>>(poS, plv, yb);
    }
    {   // out = y @ w_proj^T + b_proj
        dim3 grid(M / 128, 1024 / 128);
        gemm_nt_lds<<<grid, 256, 0, stream>>>(yb, yb, d_in[3], wpb,
                                              d_in[4], d_out, M, 1024, 1024, flag, 1, 0);
    }
    (void)in_sizes; (void)n_in; (void)out_size; (void)ws_size;
}

// Round 3
// 249.651 us; speedup vs baseline: 1.0283x; 1.0283x over previous
//
#include <hip/hip_runtime.h>
#include <hip/hip_bf16.h>

using bf16 = __hip_bfloat16;

typedef __bf16 bf16x8 __attribute__((ext_vector_type(8)));
typedef __bf16 bf16x4v __attribute__((ext_vector_type(4)));
typedef float  float4v __attribute__((ext_vector_type(4)));

#define MFMA16x16x32(a, b, c) __builtin_amdgcn_mfma_f32_16x16x32_bf16((a), (b), (c), 0, 0, 0)

#if __has_builtin(__builtin_amdgcn_exp2f)
#define EXP2F(x) __builtin_amdgcn_exp2f(x)
#else
#define EXP2F(x) exp2f(x)
#endif

#define T_SEQ 2048
#define NHEAD 16
#define CDIM  1024
#define HD3   3072

// async global->LDS, 16B per lane. LDS dest must be wave-uniform base + lane*16.
__device__ __forceinline__ void async_copy16(const void* g, void* l) {
    __builtin_amdgcn_global_load_lds(
        (__attribute__((address_space(1))) unsigned int*)g,
        (__attribute__((address_space(3))) unsigned int*)l,
        16, 0, 0);
}

__device__ __forceinline__ void atomAddF32(float* p, float v) {
    unsafeAtomicAdd(p, v);
}

// ---------------------------------------------------------------------------
// Runtime dtype probe: flag=1 -> fp32 inputs, 0 -> bf16.
// ---------------------------------------------------------------------------
__global__ __launch_bounds__(256) void detect_dtype_kernel(
    const unsigned short* __restrict__ xs, int* __restrict__ flag)
{
    __shared__ int red[256];
    int cnt = 0;
    for (int i = threadIdx.x; i < 16384; i += 256) {
        const unsigned short u = xs[i];
        const int e = (u >> 7) & 0xFF;
        if (e == 0xFF || (e != 0 && e < 0x60)) cnt++;
    }
    red[threadIdx.x] = cnt;
    __syncthreads();
    for (int s = 128; s > 0; s >>= 1) {
        if (threadIdx.x < s) red[threadIdx.x] += red[threadIdx.x + s];
        __syncthreads();
    }
    if (threadIdx.x == 0) flag[0] = (red[0] > 100) ? 1 : 0;
}

__global__ __launch_bounds__(256) void convert_f32_kernel(
    const float* __restrict__ x, const float* __restrict__ wa,
    const float* __restrict__ wp,
    bf16* __restrict__ xb, bf16* __restrict__ wab, bf16* __restrict__ wpb,
    const int* __restrict__ flag)
{
    if (flag[0] == 0) return;
    const int stride = gridDim.x * 256;
    for (int i = blockIdx.x * 256 + threadIdx.x; i < 8388608; i += stride) {
        if (i < 4194304)      xb[i] = __float2bfloat16(x[i]);
        else if (i < 7340032) wab[i - 4194304] = __float2bfloat16(wa[i - 4194304]);
        else                  wpb[i - 7340032] = __float2bfloat16(wp[i - 7340032]);
    }
}

// Zero the attention partial buffers (poS 8,388,608 B + plv 262,144 B,
// contiguous from ws+256). Launched after gemm1 (region overlays dead xb).
__global__ __launch_bounds__(256) void zero_partials(float4v* __restrict__ p)
{
    const int stride = gridDim.x * 256;
    const float4v z = {0.f, 0.f, 0.f, 0.f};
    for (int i = blockIdx.x * 256 + threadIdx.x; i < 540672; i += stride)
        p[i] = z;
}

// ---------------------------------------------------------------------------
// NT GEMM, BK=64, XOR-swizzled async staging. C[m,n]=sum_k A[m,k]B[n,k]+bias.
// Template JF = per-wave N fragments: JF=4 -> BN=128 (byte-identical to the
// proven kernel), JF=2 -> BN=64 (doubles grid for small-N gemm2 occupancy).
// scale_q: multiply (acc+bias) by 0.125*log2e for cols < 1024 (q-columns).
// ---------------------------------------------------------------------------
template<int JF>
__global__ __launch_bounds__(256) void gemm_nt_lds_t(
    const void* __restrict__ Araw, const bf16* __restrict__ Aconv,
    const void* __restrict__ Braw, const bf16* __restrict__ Bconv,
    const void* __restrict__ biasraw, void* __restrict__ Cv,
    int M, int N, int K, const int* __restrict__ flag, int is_final, int scale_q)
{
    const bool f32 = (flag[0] != 0);
    const bf16* A = f32 ? Aconv : (const bf16*)Araw;
    const bf16* B = f32 ? Bconv : (const bf16*)Bconv ? Bconv : (const bf16*)Braw;
    // (the line above must not alter semantics: recompute properly)
    B = f32 ? Bconv : (const bf16*)Braw;

    __shared__ bf16 As[128 * 64];
    __shared__ bf16 Bs[JF * 32 * 64];

    const int tid  = threadIdx.x;
    const int lane = tid & 63;
    const int wave = tid >> 6;
    const int wm = wave & 1, wn = wave >> 1;
    const int c = lane & 15, g = lane >> 4;

    const int bm = blockIdx.x * 128;
    const int bn = blockIdx.y * (JF * 32);

    const int srow = tid >> 3;
    const int slc  = ((tid & 7) ^ (srow & 7)) * 8;
    const bf16* gA = A + (size_t)(bm + srow) * K + slc;
    const bf16* gB = B + (size_t)(bn + srow) * K + slc;

    float4v acc[4][JF] = {};

    for (int k0 = 0; k0 < K; k0 += 64) {
        __syncthreads();
#pragma unroll
        for (int q = 0; q < 4; ++q)
            async_copy16(gA + k0 + (size_t)(q * 32) * K, As + q * 2048 + tid * 8);
#pragma unroll
        for (int q = 0; q < JF; ++q)
            async_copy16(gB + k0 + (size_t)(q * 32) * K, Bs + q * 2048 + tid * 8);
        __syncthreads();

#pragma unroll
        for (int kk = 0; kk < 2; ++kk) {
            bf16x8 af[4], bfr[JF];
#pragma unroll
            for (int i = 0; i < 4; ++i)
                af[i]  = *(const bf16x8*)&As[(wm * 64 + i * 16 + c) * 64 +
                                             (((kk * 4 + g) ^ (c & 7)) * 8)];
#pragma unroll
            for (int j = 0; j < JF; ++j)
                bfr[j] = *(const bf16x8*)&Bs[(wn * (JF * 16) + j * 16 + c) * 64 +
                                             (((kk * 4 + g) ^ (c & 7)) * 8)];
#pragma unroll
            for (int i = 0; i < 4; ++i)
#pragma unroll
                for (int j = 0; j < JF; ++j)
                    acc[i][j] = MFMA16x16x32(af[i], bfr[j], acc[i][j]);
        }
    }

    const bool f32o = is_final && f32;
    bf16*  Cb = (bf16*)Cv;
    float* Cf = (float*)Cv;

#pragma unroll
    for (int i = 0; i < 4; ++i) {
        const int row = bm + wm * 64 + i * 16 + g * 4;
#pragma unroll
        for (int j = 0; j < JF; ++j) {
            const int col = bn + wn * (JF * 16) + j * 16 + c;
            const float bv = f32 ? ((const float*)biasraw)[col]
                                 : __bfloat162float(((const bf16*)biasraw)[col]);
            const float sc = (scale_q && col < 1024) ? 0.18033688f : 1.0f;
            if (f32o) {
#pragma unroll
                for (int t = 0; t < 4; ++t)
                    Cf[(size_t)(row + t) * N + col] = (acc[i][j][t] + bv) * sc;
            } else {
#pragma unroll
                for (int t = 0; t < 4; ++t)
                    Cb[(size_t)(row + t) * N + col] =
                        __float2bfloat16((acc[i][j][t] + bv) * sc);
            }
        }
    }
}

// ---------------------------------------------------------------------------
// Flash attention v7: round-0's proven KT=128 inner loop + balanced key-split.
// 128-key units per bh-pair pj: heavy tile Hq=15-pj has 16-pj units, light
// tile pj has pj+1. Role A = heavy units [0,8); role B = heavy [8,16-pj) then
// all of light = 9 units. Un-maxed exp2 softmax -> disjoint-key partials
// (o,l) merge by addition (atomics into zeroed poS; merge normalizes).
// ---------------------------------------------------------------------------
__device__ __forceinline__ void attn_seg128(
    const bf16* __restrict__ kgbase, const bf16* __restrict__ vgbase,
    __bf16* __restrict__ Ks, __bf16* __restrict__ Vt,   // [2][128*64],[2][64*128]
    int u0, int uN, int qw,
    const bf16x8 qf[2][2], float4v o[2][4], float4v ol[2], int tid)
{
    const int lane = tid & 63;
    const int c = lane & 15, g = lane >> 4;
    const int krow = tid >> 3;
    const int klc  = ((tid & 7) ^ (krow & 7)) * 8;
    const int kq   = tid & 31;
    const int dgv  = tid >> 5;
    const int vchunk = (kq >> 3) * 4 + (kq & 3);
    const int vlow   = ((kq >> 2) & 1) * 4;

    bf16x8 ones;
#pragma unroll
    for (int ii = 0; ii < 8; ++ii) ones[ii] = (__bf16)1.0f;

    // prologue: stage unit u0 into buffer 0
#pragma unroll
    for (int q = 0; q < 4; ++q)
        async_copy16(kgbase + (size_t)(u0 * 128 + q * 32 + krow) * HD3 + klc,
                     Ks + q * 2048 + tid * 8);
    {
        bf16x8 vr[4];
#pragma unroll
        for (int r = 0; r < 4; ++r)
            vr[r] = *(const bf16x8*)(vgbase + (size_t)(u0 * 128 + kq * 4 + r) * HD3 + dgv * 8);
#pragma unroll
        for (int jj = 0; jj < 8; ++jj) {
            const int d = dgv * 8 + jj;
            bf16x4v pk;
#pragma unroll
            for (int r = 0; r < 4; ++r) pk[r] = vr[r][jj];
            *(bf16x4v*)&Vt[d * 128 + ((vchunk ^ (d & 7)) << 3) + vlow] = pk;
        }
    }
    __syncthreads();

    int b = 0;
    for (int u = u0; u < uN; ++u, b ^= 1) {
        const int kt = u * 128;
        const bool more = (u + 1 < uN);
        bf16x8 vr[4];
        if (more) {
#pragma unroll
            for (int q = 0; q < 4; ++q)
                async_copy16(kgbase + (size_t)(kt + 128 + q * 32 + krow) * HD3 + klc,
                             Ks + (b ^ 1) * 8192 + q * 2048 + tid * 8);
#pragma unroll
            for (int r = 0; r < 4; ++r)
                vr[r] = *(const bf16x8*)(vgbase + (size_t)(kt + 128 + kq * 4 + r) * HD3 + dgv * 8);
        }

#pragma unroll
        for (int hf = 0; hf < 2; ++hf) {
            if (kt + hf * 64 > qw + 31) continue;   // whole half masked for wave
            const __bf16* Kb = Ks + b * 8192;
            const __bf16* Vb = Vt + b * 8192;

            // ---- S^T = K Q^T over 64 keys ----
            float4v sacc[2][4] = {};
#pragma unroll
            for (int jb = 0; jb < 4; ++jb) {
                const int key = hf * 64 + jb * 16 + c;
                bf16x8 a0 = *(const bf16x8*)&Kb[key * 64 + ((g ^ (c & 7)) * 8)];
                bf16x8 a1 = *(const bf16x8*)&Kb[key * 64 + (((4 + g) ^ (c & 7)) * 8)];
#pragma unroll
                for (int a = 0; a < 2; ++a) {
                    sacc[a][jb] = MFMA16x16x32(a0, qf[a][0], sacc[a][jb]);
                    sacc[a][jb] = MFMA16x16x32(a1, qf[a][1], sacc[a][jb]);
                }
            }
            // ---- mask + exp2 + pack P (registers only) ----
            bf16x8 pf[2][2];
#pragma unroll
            for (int a = 0; a < 2; ++a) {
                const int qmin = qw + a * 16;
                if (kt + hf * 64 + 63 > qmin) {
                    const int query = qmin + c;
#pragma unroll
                    for (int jb = 0; jb < 4; ++jb) {
                        const int kb = kt + hf * 64 + jb * 16 + g * 4;
#pragma unroll
                        for (int t = 0; t < 4; ++t)
                            if (kb + t > query) sacc[a][jb][t] = -1e30f;
                    }
                }
#pragma unroll
                for (int jb = 0; jb < 4; ++jb)
#pragma unroll
                    for (int t = 0; t < 4; ++t)
                        sacc[a][jb][t] = EXP2F(sacc[a][jb][t]);
#pragma unroll
                for (int lkf = 0; lkf < 2; ++lkf) {
                    bf16x8 pk;
#pragma unroll
                    for (int jj = 0; jj < 8; ++jj)
                        pk[jj] = (__bf16)sacc[a][lkf * 2 + (jj >> 2)][jj & 3];
                    pf[a][lkf] = pk;
                }
            }
            // ---- O^T += V^T P ; lsum += 1^T P (this half) ----
#pragma unroll
            for (int lkf = 0; lkf < 2; ++lkf) {
                const int kf = hf * 2 + lkf;
                ol[0] = MFMA16x16x32(ones, pf[0][lkf], ol[0]);
                ol[1] = MFMA16x16x32(ones, pf[1][lkf], ol[1]);
#pragma unroll
                for (int dn = 0; dn < 4; ++dn) {
                    const int d = dn * 16 + c;
                    bf16x8 vf = *(const bf16x8*)
                        &Vb[d * 128 + (((kf * 4 + g) ^ (d & 7)) << 3)];
                    o[0][dn] = MFMA16x16x32(vf, pf[0][lkf], o[0][dn]);
                    o[1][dn] = MFMA16x16x32(vf, pf[1][lkf], o[1][dn]);
                }
            }
        }

        if (more) {
            __bf16* Vn = Vt + (b ^ 1) * 8192;
#pragma unroll
            for (int jj = 0; jj < 8; ++jj) {
                const int d = dgv * 8 + jj;
                bf16x4v pk;
#pragma unroll
                for (int r = 0; r < 4; ++r) pk[r] = vr[r][jj];
                *(bf16x4v*)&Vn[d * 128 + ((vchunk ^ (d & 7)) << 3) + vlow] = pk;
            }
        }
        __syncthreads();
    }
}

__global__ __launch_bounds__(256) void attn_ks128(
    const bf16* __restrict__ qkv, bf16* __restrict__ y,
    float* __restrict__ poS, float* __restrict__ plv)
{
    __shared__ __bf16 Ks[2 * 128 * 64];
    __shared__ __bf16 Vt[2 * 64 * 128];

    const int tid  = threadIdx.x;
    const int lane = tid & 63;
    const int w    = tid >> 6;
    const int c    = lane & 15;
    const int g    = lane >> 4;

    // XCD-aware decode (proven round 2): blocks with bh === xcd (mod 8)
    // share an XCD -> K/V L2-resident. Bijective over 512.
    const int jid  = blockIdx.x;
    const int xcd  = jid & 7;
    const int rank = jid >> 3;
    const int bh   = ((rank & 3) << 3) | xcd;   // 0..31
    const int pr   = rank >> 2;                 // 0..15
    const int pj   = pr >> 1;                   // pair 0..7
    const int role = pr & 1;                    // 0=A, 1=B

    const int bb = bh >> 4, h = bh & 15;
    const size_t base = (size_t)bb * T_SEQ * HD3 + (size_t)h * 64;
    const bf16* kgbase = qkv + base + 1024;
    const bf16* vgbase = qkv + base + 2048;

    const int Hq = 15 - pj;
    const int s  = bh * 8 + pj;                 // heavy-tile merge slot

    // ---- heavy q-tile segment (A: units [0,8); B: [8, 16-pj)) ----
    {
        const int qw = Hq * 128 + w * 32;
        bf16x8 qf[2][2];
#pragma unroll
        for (int a = 0; a < 2; ++a)
#pragma unroll
            for (int k2 = 0; k2 < 2; ++k2)
                qf[a][k2] = *(const bf16x8*)(qkv + base
                    + (size_t)(qw + a * 16 + c) * HD3 + k2 * 32 + g * 8);

        float4v o[2][4] = {};
        float4v ol[2]   = {};
        const int u0 = role ? 8 : 0;
        const int uN = role ? (16 - pj) : 8;
        attn_seg128(kgbase, vgbase, Ks, Vt, u0, uN, qw, qf, o, ol, tid);

        float* po = poS + (size_t)s * 8192;
        float* pl = plv + (size_t)(s * 2 + role) * 128;
#pragma unroll
        for (int a = 0; a < 2; ++a) {
            const int qr = w * 32 + a * 16 + c;
#pragma unroll
            for (int dn = 0; dn < 4; ++dn)
#pragma unroll
                for (int t = 0; t < 4; ++t)
                    atomAddF32(&po[(size_t)qr * 64 + dn * 16 + g * 4 + t],
                               o[a][dn][t]);
            if (g == 0) pl[qr] = ol[a].x;
        }
    }

    // ---- light q-tile (role B only): units [0, pj+1), finalized here ----
    if (role) {
        const int qw = pj * 128 + w * 32;
        bf16x8 qf[2][2];
#pragma unroll
        for (int a = 0; a < 2; ++a)
#pragma unroll
            for (int k2 = 0; k2 < 2; ++k2)
                qf[a][k2] = *(const bf16x8*)(qkv + base
                    + (size_t)(qw + a * 16 + c) * HD3 + k2 * 32 + g * 8);

        float4v o[2][4] = {};
        float4v ol[2]   = {};
        attn_seg128(kgbase, vgbase, Ks, Vt, 0, pj + 1, qw, qf, o, ol, tid);

#pragma unroll
        for (int a = 0; a < 2; ++a) {
            const float linv = 1.f / ol[a].x;
            const int q = qw + a * 16 + c;
            const size_t yb = ((size_t)bb * T_SEQ + q) * CDIM + h * 64;
#pragma unroll
            for (int dn = 0; dn < 4; ++dn) {
                bf16x4v ov;
#pragma unroll
                for (int t = 0; t < 4; ++t)
                    ov[t] = (__bf16)(o[a][dn][t] * linv);
                *(bf16x4v*)&y[yb + dn * 16 + g * 4] = ov;
            }
        }
    }
}

// Normalize each heavy q-tile: o = poS (sum of both roles), l = lA+lB.
__global__ __launch_bounds__(256) void attn_merge(
    const float* __restrict__ poS, const float* __restrict__ plv,
    bf16* __restrict__ y)
{
    const int s  = blockIdx.x;          // 0..255
    const int bh = s >> 3, pj = s & 7;
    const int Hq = 15 - pj;
    const int bb = bh >> 4, h = bh & 15;

    const float4v* A  = (const float4v*)(poS + (size_t)s * 8192);
    const float* la = plv + (size_t)(s * 2) * 128;
    const float* lb = la + 128;

    for (int idx = threadIdx.x; idx < 2048; idx += 256) {
        const int row = idx >> 4;           // 16 float4 per 64-dim row
        const int d0  = (idx & 15) * 4;
        const float linv = 1.f / (la[row] + lb[row]);
        float4v v = A[idx];
        bf16x4v ov;
#pragma unroll
        for (int t = 0; t < 4; ++t) ov[t] = (__bf16)(v[t] * linv);
        const int q = Hq * 128 + row;
        *(bf16x4v*)&y[((size_t)bb * T_SEQ + q) * CDIM + h * 64 + d0] = ov;
    }
}

// ---------------------------------------------------------------------------
extern "C" void kernel_launch(void* const* d_in, const int* in_sizes, int n_in,
                              void* d_out, int out_size, void* d_ws, size_t ws_size,
                              hipStream_t stream)
{
    const int M = 4096;   // B*T
    char* ws = (char*)d_ws;

    // Footprint identical to the proven baseline: max offset 50,331,904 B.
    int*  flag = (int*)ws;                        // 256 B
    bf16* xb   = (bf16*)(ws + 256);               // 8 MB   (dead after gemm1)
    bf16* wab  = (bf16*)(ws + 8388864);           // 6 MB   (dead after gemm1)
    bf16* wpb  = (bf16*)(ws + 14680320);          // 2 MB
    bf16* qkv  = (bf16*)(ws + 16777472);          // 25.2 MB
    bf16* yb   = (bf16*)(ws + 41943296);          // 8 MB -> end 50,331,904
    // attn partials overlay the dead xb/wab region (zeroed after gemm1):
    float* poS = (float*)(ws + 256);              // 8,388,608 B (exact xb fit)
    float* plv = (float*)(ws + 8388864);          // 262,144 B (wab head)

    detect_dtype_kernel<<<1, 256, 0, stream>>>((const unsigned short*)d_in[0], flag);

    convert_f32_kernel<<<512, 256, 0, stream>>>(
        (const float*)d_in[0], (const float*)d_in[1], (const float*)d_in[3],
        xb, wab, wpb, flag);

    {   // qkv = x @ w_attn^T + b_attn  (q columns pre-scaled), BN=128 proven path
        dim3 grid(M / 128, 3072 / 128);
        gemm_nt_lds_t<4><<<grid, 256, 0, stream>>>(d_in[0], xb, d_in[1], wab,
                                                   d_in[2], qkv, M, 3072, 1024, flag, 0, 1);
    }

    // zero partial buffers (xb/wab now dead; stream-ordered before atomics)
    zero_partials<<<512, 256, 0, stream>>>((float4v*)(ws + 256));

    {   // flash attention: KT=128 inner loop + balanced key-split (8/9 units)
        attn_ks128<<<512, 256, 0, stream>>>(qkv, yb, poS, plv);
        attn_merge<<<256, 256, 0, stream>>>(poS, plv, yb);
    }
    {   // out = y @ w_proj^T + b_proj, BN=64 -> 512 blocks = 2 blocks/CU
        dim3 grid(M / 128, 1024 / 64);
        gemm_nt_lds_t<2><<<grid, 256, 0, stream>>>(yb, yb, d_in[3], wpb,
                                                   d_in[4], d_out, M, 1024, 1024, flag, 1, 0);
    }
    (void)in_sizes; (void)n_in; (void)out_size; (void)ws_size;
}

// Round 4
// 212.223 us; speedup vs baseline: 1.2096x; 1.1764x over previous
//
#include <hip/hip_runtime.h>
#include <hip/hip_bf16.h>

using bf16 = __hip_bfloat16;

typedef __bf16 bf16x8 __attribute__((ext_vector_type(8)));
typedef __bf16 bf16x4v __attribute__((ext_vector_type(4)));
typedef float  float4v __attribute__((ext_vector_type(4)));

#define MFMA16x16x32(a, b, c) __builtin_amdgcn_mfma_f32_16x16x32_bf16((a), (b), (c), 0, 0, 0)

#if __has_builtin(__builtin_amdgcn_exp2f)
#define EXP2F(x) __builtin_amdgcn_exp2f(x)
#else
#define EXP2F(x) exp2f(x)
#endif

#define T_SEQ 2048
#define NHEAD 16
#define CDIM  1024
#define HD3   3072

// async global->LDS, 16B per lane. LDS dest must be wave-uniform base + lane*16.
__device__ __forceinline__ void async_copy16(const void* g, void* l) {
    __builtin_amdgcn_global_load_lds(
        (__attribute__((address_space(1))) unsigned int*)g,
        (__attribute__((address_space(3))) unsigned int*)l,
        16, 0, 0);
}

// ---------------------------------------------------------------------------
// Runtime dtype probe: flag=1 -> fp32 inputs, 0 -> bf16.
// ---------------------------------------------------------------------------
__global__ __launch_bounds__(256) void detect_dtype_kernel(
    const unsigned short* __restrict__ xs, int* __restrict__ flag)
{
    __shared__ int red[256];
    int cnt = 0;
    for (int i = threadIdx.x; i < 16384; i += 256) {
        const unsigned short u = xs[i];
        const int e = (u >> 7) & 0xFF;
        if (e == 0xFF || (e != 0 && e < 0x60)) cnt++;
    }
    red[threadIdx.x] = cnt;
    __syncthreads();
    for (int s = 128; s > 0; s >>= 1) {
        if (threadIdx.x < s) red[threadIdx.x] += red[threadIdx.x + s];
        __syncthreads();
    }
    if (threadIdx.x == 0) flag[0] = (red[0] > 100) ? 1 : 0;
}

__global__ __launch_bounds__(256) void convert_f32_kernel(
    const float* __restrict__ x, const float* __restrict__ wa,
    const float* __restrict__ wp,
    bf16* __restrict__ xb, bf16* __restrict__ wab, bf16* __restrict__ wpb,
    const int* __restrict__ flag)
{
    if (flag[0] == 0) return;
    const int stride = gridDim.x * 256;
    for (int i = blockIdx.x * 256 + threadIdx.x; i < 8388608; i += stride) {
        if (i < 4194304)      xb[i] = __float2bfloat16(x[i]);
        else if (i < 7340032) wab[i - 4194304] = __float2bfloat16(wa[i - 4194304]);
        else                  wpb[i - 7340032] = __float2bfloat16(wp[i - 7340032]);
    }
}

// ---------------------------------------------------------------------------
// NT GEMM, BK=64, XOR-swizzled async staging. C[m,n]=sum_k A[m,k]B[n,k]+bias.
// JF = per-wave N fragments: JF=4 -> BN=128 (proven gemm1 path),
// JF=2 -> BN=64 (harness-verified round 3; 2 blocks/CU for gemm2).
// swz: bijective XCD remap (requires gridDim.x*gridDim.y % 8 == 0).
// scale_q: multiply (acc+bias) by 0.125*log2e for cols < 1024 (q-columns).
// ---------------------------------------------------------------------------
template<int JF>
__global__ __launch_bounds__(256) void gemm_nt_lds_t(
    const void* __restrict__ Araw, const bf16* __restrict__ Aconv,
    const void* __restrict__ Braw, const bf16* __restrict__ Bconv,
    const void* __restrict__ biasraw, void* __restrict__ Cv,
    int M, int N, int K, const int* __restrict__ flag, int is_final,
    int scale_q, int swz)
{
    const bool f32 = (flag[0] != 0);
    const bf16* A = f32 ? Aconv : (const bf16*)Araw;
    const bf16* B = f32 ? Bconv : (const bf16*)Braw;

    __shared__ bf16 As[128 * 64];
    __shared__ bf16 Bs[JF * 32 * 64];

    const int tid  = threadIdx.x;
    const int lane = tid & 63;
    const int wave = tid >> 6;
    const int wm = wave & 1, wn = wave >> 1;
    const int c = lane & 15, g = lane >> 4;

    int bx = blockIdx.x, by = blockIdx.y;
    if (swz) {
        const int nwg = gridDim.x * gridDim.y;
        const int lin = by * gridDim.x + bx;
        const int nl  = (lin & 7) * (nwg >> 3) + (lin >> 3);
        bx = nl % gridDim.x;
        by = nl / gridDim.x;
    }
    const int bm = bx * 128;
    const int bn = by * (JF * 32);

    const int srow = tid >> 3;
    const int slc  = ((tid & 7) ^ (srow & 7)) * 8;
    const bf16* gA = A + (size_t)(bm + srow) * K + slc;
    const bf16* gB = B + (size_t)(bn + srow) * K + slc;

    float4v acc[4][JF] = {};

    for (int k0 = 0; k0 < K; k0 += 64) {
        __syncthreads();
#pragma unroll
        for (int q = 0; q < 4; ++q)
            async_copy16(gA + k0 + (size_t)(q * 32) * K, As + q * 2048 + tid * 8);
#pragma unroll
        for (int q = 0; q < JF; ++q)
            async_copy16(gB + k0 + (size_t)(q * 32) * K, Bs + q * 2048 + tid * 8);
        __syncthreads();

#pragma unroll
        for (int kk = 0; kk < 2; ++kk) {
            bf16x8 af[4], bfr[JF];
#pragma unroll
            for (int i = 0; i < 4; ++i)
                af[i]  = *(const bf16x8*)&As[(wm * 64 + i * 16 + c) * 64 +
                                             (((kk * 4 + g) ^ (c & 7)) * 8)];
#pragma unroll
            for (int j = 0; j < JF; ++j)
                bfr[j] = *(const bf16x8*)&Bs[(wn * (JF * 16) + j * 16 + c) * 64 +
                                             (((kk * 4 + g) ^ (c & 7)) * 8)];
#pragma unroll
            for (int i = 0; i < 4; ++i)
#pragma unroll
                for (int j = 0; j < JF; ++j)
                    acc[i][j] = MFMA16x16x32(af[i], bfr[j], acc[i][j]);
        }
    }

    const bool f32o = is_final && f32;
    bf16*  Cb = (bf16*)Cv;
    float* Cf = (float*)Cv;

#pragma unroll
    for (int i = 0; i < 4; ++i) {
        const int row = bm + wm * 64 + i * 16 + g * 4;
#pragma unroll
        for (int j = 0; j < JF; ++j) {
            const int col = bn + wn * (JF * 16) + j * 16 + c;
            const float bv = f32 ? ((const float*)biasraw)[col]
                                 : __bfloat162float(((const bf16*)biasraw)[col]);
            const float sc = (scale_q && col < 1024) ? 0.18033688f : 1.0f;
            if (f32o) {
#pragma unroll
                for (int t = 0; t < 4; ++t)
                    Cf[(size_t)(row + t) * N + col] = (acc[i][j][t] + bv) * sc;
            } else {
#pragma unroll
                for (int t = 0; t < 4; ++t)
                    Cb[(size_t)(row + t) * N + col] =
                        __float2bfloat16((acc[i][j][t] + bv) * sc);
            }
        }
    }
}

// ---------------------------------------------------------------------------
// MFMA flash attention v8 = round-0's proven kernel with:
//  (1) dispatch remap keeping the heavy/light pairing (ids i and i+256 land
//      same-XCD same-CU-slot) while forcing XCD = id%8 = bh&7 -> the 4 bh
//      per XCD keep K/V/Q (~3MB) L2-resident (round-2-verified FETCH cut);
//  (2) s_setprio(1) around the MFMA clusters (m191: +4-7% attn).
// Heavy q-tiles (15-j) pair with light (j): co-resident pairs sum to 17.
// ---------------------------------------------------------------------------
__global__ __launch_bounds__(256) void attn_mfma(
    const bf16* __restrict__ qkv, bf16* __restrict__ y)
{
    __shared__ __bf16 Ks[2][128 * 64];   // [buf][key][dim], chunk ^ (key&7)
    __shared__ __bf16 Vt[2][64 * 128];   // [buf][dim][kappa], chunk ^ (dim&7)

    const int tid  = threadIdx.x;
    const int lane = tid & 63;
    const int w    = tid >> 6;
    const int c    = lane & 15;
    const int g    = lane >> 4;

    // decode: i = role*256 + ((j*4 + bh_hi)<<3 | bh_lo)
    const int i    = blockIdx.x;
    const int role = i >> 8;             // 0 = heavy, 1 = light
    const int bhl  = i & 7;              // bh low 3 bits == XCD id
    const int t5   = (i & 255) >> 3;     // 0..31
    const int j    = t5 >> 2;            // 0..7
    const int bh   = ((t5 & 3) << 3) | bhl;
    const int qblk = role ? j : (15 - j);
    const int bb   = bh >> 4;
    const int h    = bh & 15;
    const size_t base = (size_t)bb * T_SEQ * HD3 + (size_t)h * 64;

    // staging indices
    const int krow = tid >> 3;                       // K: 0..31 (+ q*32)
    const int klc  = ((tid & 7) ^ (krow & 7)) * 8;   // K: logical dim col
    const int kq   = tid & 31;                       // V: key group
    const int dgv  = tid >> 5;                       // V: dim group 0..7
    const int vchunk = (kq >> 3) * 4 + (kq & 3);
    const int vlow   = ((kq >> 2) & 1) * 4;

    const bf16* kgbase = qkv + base + 1024;
    const bf16* vgbase = qkv + base + 2048;

    bf16x8 ones;
#pragma unroll
    for (int ii = 0; ii < 8; ++ii) ones[ii] = (__bf16)1.0f;

    const int q0 = qblk * 128;
    const int qw = q0 + w * 32;          // wave query origin

    // Q B-fragments (pre-scaled by 0.125*log2e in gemm1 epilogue)
    bf16x8 qf[2][2];
#pragma unroll
    for (int a = 0; a < 2; ++a)
#pragma unroll
        for (int kf2 = 0; kf2 < 2; ++kf2)
            qf[a][kf2] = *(const bf16x8*)(qkv + base
                + (size_t)(qw + a * 16 + c) * HD3 + kf2 * 32 + g * 8);

    float4v o[2][4] = {};
    float4v ol[2] = {};                  // lsum via ones-MFMA

    // ---- prologue: stage tile 0 into buf 0 ----
#pragma unroll
    for (int q = 0; q < 4; ++q)
        async_copy16(kgbase + (size_t)(q * 32 + krow) * HD3 + klc,
                     &Ks[0][q * 2048 + tid * 8]);
    {
        bf16x8 vr[4];
#pragma unroll
        for (int r = 0; r < 4; ++r)
            vr[r] = *(const bf16x8*)(vgbase + (size_t)(kq * 4 + r) * HD3 + dgv * 8);
#pragma unroll
        for (int jj = 0; jj < 8; ++jj) {
            const int d = dgv * 8 + jj;
            bf16x4v pk;
#pragma unroll
            for (int r = 0; r < 4; ++r) pk[r] = vr[r][jj];
            *(bf16x4v*)&Vt[0][d * 128 + ((vchunk ^ (d & 7)) << 3) + vlow] = pk;
        }
    }
    __syncthreads();

    int b = 0;
    for (int kt = 0; kt <= q0; kt += 128, b ^= 1) {
        const bool more = (kt + 128 <= q0);
        bf16x8 vr[4];
        if (more) {
#pragma unroll
            for (int q = 0; q < 4; ++q)
                async_copy16(kgbase + (size_t)(kt + 128 + q * 32 + krow) * HD3 + klc,
                             &Ks[b ^ 1][q * 2048 + tid * 8]);
#pragma unroll
            for (int r = 0; r < 4; ++r)
                vr[r] = *(const bf16x8*)(vgbase + (size_t)(kt + 128 + kq * 4 + r) * HD3 + dgv * 8);
        }

#pragma unroll
        for (int hf = 0; hf < 2; ++hf) {
            if (kt + hf * 64 > qw + 31) continue;   // whole half masked for wave

            // ---- S^T = K Q^T over 64 keys ----
            float4v sacc[2][4] = {};
            __builtin_amdgcn_s_setprio(1);
#pragma unroll
            for (int jb = 0; jb < 4; ++jb) {
                const int key = hf * 64 + jb * 16 + c;
                bf16x8 a0 = *(const bf16x8*)&Ks[b][key * 64 + ((g ^ (c & 7)) * 8)];
                bf16x8 a1 = *(const bf16x8*)&Ks[b][key * 64 + (((4 + g) ^ (c & 7)) * 8)];
#pragma unroll
                for (int a = 0; a < 2; ++a) {
                    sacc[a][jb] = MFMA16x16x32(a0, qf[a][0], sacc[a][jb]);
                    sacc[a][jb] = MFMA16x16x32(a1, qf[a][1], sacc[a][jb]);
                }
            }
            __builtin_amdgcn_s_setprio(0);
            // ---- mask + exp2 + pack P (registers only) ----
            bf16x8 pf[2][2];
#pragma unroll
            for (int a = 0; a < 2; ++a) {
                const int qmin = qw + a * 16;
                if (kt + hf * 64 + 63 > qmin) {
                    const int query = qmin + c;
#pragma unroll
                    for (int jb = 0; jb < 4; ++jb) {
                        const int kb = kt + hf * 64 + jb * 16 + g * 4;
#pragma unroll
                        for (int t = 0; t < 4; ++t)
                            if (kb + t > query) sacc[a][jb][t] = -1e30f;
                    }
                }
#pragma unroll
                for (int jb = 0; jb < 4; ++jb)
#pragma unroll
                    for (int t = 0; t < 4; ++t)
                        sacc[a][jb][t] = EXP2F(sacc[a][jb][t]);
#pragma unroll
                for (int lkf = 0; lkf < 2; ++lkf) {
                    bf16x8 pk;
#pragma unroll
                    for (int jj = 0; jj < 8; ++jj)
                        pk[jj] = (__bf16)sacc[a][lkf * 2 + (jj >> 2)][jj & 3];
                    pf[a][lkf] = pk;
                }
            }
            // ---- O^T += V^T P ; lsum += 1^T P (this half) ----
            __builtin_amdgcn_s_setprio(1);
#pragma unroll
            for (int lkf = 0; lkf < 2; ++lkf) {
                const int kf = hf * 2 + lkf;
                ol[0] = MFMA16x16x32(ones, pf[0][lkf], ol[0]);
                ol[1] = MFMA16x16x32(ones, pf[1][lkf], ol[1]);
#pragma unroll
                for (int dn = 0; dn < 4; ++dn) {
                    const int d = dn * 16 + c;
                    bf16x8 vf = *(const bf16x8*)
                        &Vt[b][d * 128 + (((kf * 4 + g) ^ (d & 7)) << 3)];
                    o[0][dn] = MFMA16x16x32(vf, pf[0][lkf], o[0][dn]);
                    o[1][dn] = MFMA16x16x32(vf, pf[1][lkf], o[1][dn]);
                }
            }
            __builtin_amdgcn_s_setprio(0);
        }

        if (more) {
#pragma unroll
            for (int jj = 0; jj < 8; ++jj) {
                const int d = dgv * 8 + jj;
                bf16x4v pk;
#pragma unroll
                for (int r = 0; r < 4; ++r) pk[r] = vr[r][jj];
                *(bf16x4v*)&Vt[b ^ 1][d * 128 + ((vchunk ^ (d & 7)) << 3) + vlow] = pk;
            }
        }
        __syncthreads();
    }

    // ---- store: lane holds query q (col c), dims dn*16+g*4+t ----
#pragma unroll
    for (int a = 0; a < 2; ++a) {
        const float linv = 1.f / ol[a].x;
        const int q = qw + a * 16 + c;
        const size_t yb = ((size_t)bb * T_SEQ + q) * CDIM + h * 64;
#pragma unroll
        for (int dn = 0; dn < 4; ++dn) {
            bf16x4v ov;
#pragma unroll
            for (int t = 0; t < 4; ++t)
                ov[t] = (__bf16)(o[a][dn][t] * linv);
            *(bf16x4v*)&y[yb + dn * 16 + g * 4] = ov;
        }
    }
}

// ---------------------------------------------------------------------------
extern "C" void kernel_launch(void* const* d_in, const int* in_sizes, int n_in,
                              void* d_out, int out_size, void* d_ws, size_t ws_size,
                              hipStream_t stream)
{
    const int M = 4096;   // B*T
    char* ws = (char*)d_ws;

    // Footprint identical to the proven baseline: max offset 50,331,904 B.
    int*  flag = (int*)ws;                        // 256 B
    bf16* xb   = (bf16*)(ws + 256);               // 8 MB
    bf16* wab  = (bf16*)(ws + 8388864);           // 6 MB
    bf16* wpb  = (bf16*)(ws + 14680320);          // 2 MB
    bf16* qkv  = (bf16*)(ws + 16777472);          // 25.2 MB
    bf16* yb   = (bf16*)(ws + 41943296);          // 8 MB -> end 50,331,904

    detect_dtype_kernel<<<1, 256, 0, stream>>>((const unsigned short*)d_in[0], flag);

    convert_f32_kernel<<<512, 256, 0, stream>>>(
        (const float*)d_in[0], (const float*)d_in[1], (const float*)d_in[3],
        xb, wab, wpb, flag);

    {   // qkv = x @ w_attn^T + b_attn (q pre-scaled); BN=128, XCD-swizzled
        dim3 grid(M / 128, 3072 / 128);   // 768 blocks, %8==0
        gemm_nt_lds_t<4><<<grid, 256, 0, stream>>>(d_in[0], xb, d_in[1], wab,
                                                   d_in[2], qkv, M, 3072, 1024,
                                                   flag, 0, 1, 1);
    }
    {   // flash attention: round-0 schedule + bh-XCD locality + setprio
        attn_mfma<<<512, 256, 0, stream>>>(qkv, yb);
    }
    {   // out = y @ w_proj^T + b_proj; BN=64 (2 blocks/CU), XCD-swizzled
        dim3 grid(M / 128, 1024 / 64);    // 512 blocks, %8==0
        gemm_nt_lds_t<2><<<grid, 256, 0, stream>>>(yb, yb, d_in[3], wpb,
                                                   d_in[4], d_out, M, 1024, 1024,
                                                   flag, 1, 0, 1);
    }
    (void)in_sizes; (void)n_in; (void)out_size; (void)ws_size;
}

// Round 5
// 199.365 us; speedup vs baseline: 1.2876x; 1.0645x over previous
//
#include <hip/hip_runtime.h>
#include <hip/hip_bf16.h>

using bf16 = __hip_bfloat16;

typedef __bf16 bf16x8 __attribute__((ext_vector_type(8)));
typedef __bf16 bf16x4v __attribute__((ext_vector_type(4)));
typedef float  float4v __attribute__((ext_vector_type(4)));

#define MFMA16x16x32(a, b, c) __builtin_amdgcn_mfma_f32_16x16x32_bf16((a), (b), (c), 0, 0, 0)

#if __has_builtin(__builtin_amdgcn_exp2f)
#define EXP2F(x) __builtin_amdgcn_exp2f(x)
#else
#define EXP2F(x) exp2f(x)
#endif

#define T_SEQ 2048
#define NHEAD 16
#define CDIM  1024
#define HD3   3072

// async global->LDS, 16B per lane. LDS dest must be wave-uniform base + lane*16.
__device__ __forceinline__ void async_copy16(const void* g, void* l) {
    __builtin_amdgcn_global_load_lds(
        (__attribute__((address_space(1))) unsigned int*)g,
        (__attribute__((address_space(3))) unsigned int*)l,
        16, 0, 0);
}

// ---------------------------------------------------------------------------
// Runtime dtype probe: flag=1 -> fp32 inputs, 0 -> bf16.
// ---------------------------------------------------------------------------
__global__ __launch_bounds__(256) void detect_dtype_kernel(
    const unsigned short* __restrict__ xs, int* __restrict__ flag)
{
    __shared__ int red[256];
    int cnt = 0;
    for (int i = threadIdx.x; i < 16384; i += 256) {
        const unsigned short u = xs[i];
        const int e = (u >> 7) & 0xFF;
        if (e == 0xFF || (e != 0 && e < 0x60)) cnt++;
    }
    red[threadIdx.x] = cnt;
    __syncthreads();
    for (int s = 128; s > 0; s >>= 1) {
        if (threadIdx.x < s) red[threadIdx.x] += red[threadIdx.x + s];
        __syncthreads();
    }
    if (threadIdx.x == 0) flag[0] = (red[0] > 100) ? 1 : 0;
}

__global__ __launch_bounds__(256) void convert_f32_kernel(
    const float* __restrict__ x, const float* __restrict__ wa,
    const float* __restrict__ wp,
    bf16* __restrict__ xb, bf16* __restrict__ wab, bf16* __restrict__ wpb,
    const int* __restrict__ flag)
{
    if (flag[0] == 0) return;
    const int stride = gridDim.x * 256;
    for (int i = blockIdx.x * 256 + threadIdx.x; i < 8388608; i += stride) {
        if (i < 4194304)      xb[i] = __float2bfloat16(x[i]);
        else if (i < 7340032) wab[i - 4194304] = __float2bfloat16(wa[i - 4194304]);
        else                  wpb[i - 7340032] = __float2bfloat16(wp[i - 7340032]);
    }
}

// ---------------------------------------------------------------------------
// NT GEMM, BK=64, XOR-swizzled async staging. C[m,n]=sum_k A[m,k]B[n,k]+bias.
// JF = per-wave N fragments: JF=4 -> BN=128 (proven gemm1 path),
// JF=2 -> BN=64 (harness-verified; 2 blocks/CU for gemm2).
// swz: bijective XCD remap (requires gridDim.x*gridDim.y % 8 == 0).
// scale_q: multiply (acc+bias) by 0.125*log2e for cols < 1024 (q-columns).
// ---------------------------------------------------------------------------
template<int JF>
__global__ __launch_bounds__(256) void gemm_nt_lds_t(
    const void* __restrict__ Araw, const bf16* __restrict__ Aconv,
    const void* __restrict__ Braw, const bf16* __restrict__ Bconv,
    const void* __restrict__ biasraw, void* __restrict__ Cv,
    int M, int N, int K, const int* __restrict__ flag, int is_final,
    int scale_q, int swz)
{
    const bool f32 = (flag[0] != 0);
    const bf16* A = f32 ? Aconv : (const bf16*)Araw;
    const bf16* B = f32 ? Bconv : (const bf16*)Braw;

    __shared__ bf16 As[128 * 64];
    __shared__ bf16 Bs[JF * 32 * 64];

    const int tid  = threadIdx.x;
    const int lane = tid & 63;
    const int wave = tid >> 6;
    const int wm = wave & 1, wn = wave >> 1;
    const int c = lane & 15, g = lane >> 4;

    int bx = blockIdx.x, by = blockIdx.y;
    if (swz) {
        const int nwg = gridDim.x * gridDim.y;
        const int lin = by * gridDim.x + bx;
        const int nl  = (lin & 7) * (nwg >> 3) + (lin >> 3);
        bx = nl % gridDim.x;
        by = nl / gridDim.x;
    }
    const int bm = bx * 128;
    const int bn = by * (JF * 32);

    const int srow = tid >> 3;
    const int slc  = ((tid & 7) ^ (srow & 7)) * 8;
    const bf16* gA = A + (size_t)(bm + srow) * K + slc;
    const bf16* gB = B + (size_t)(bn + srow) * K + slc;

    float4v acc[4][JF] = {};

    for (int k0 = 0; k0 < K; k0 += 64) {
        __syncthreads();
#pragma unroll
        for (int q = 0; q < 4; ++q)
            async_copy16(gA + k0 + (size_t)(q * 32) * K, As + q * 2048 + tid * 8);
#pragma unroll
        for (int q = 0; q < JF; ++q)
            async_copy16(gB + k0 + (size_t)(q * 32) * K, Bs + q * 2048 + tid * 8);
        __syncthreads();

#pragma unroll
        for (int kk = 0; kk < 2; ++kk) {
            bf16x8 af[4], bfr[JF];
#pragma unroll
            for (int i = 0; i < 4; ++i)
                af[i]  = *(const bf16x8*)&As[(wm * 64 + i * 16 + c) * 64 +
                                             (((kk * 4 + g) ^ (c & 7)) * 8)];
#pragma unroll
            for (int j = 0; j < JF; ++j)
                bfr[j] = *(const bf16x8*)&Bs[(wn * (JF * 16) + j * 16 + c) * 64 +
                                             (((kk * 4 + g) ^ (c & 7)) * 8)];
#pragma unroll
            for (int i = 0; i < 4; ++i)
#pragma unroll
                for (int j = 0; j < JF; ++j)
                    acc[i][j] = MFMA16x16x32(af[i], bfr[j], acc[i][j]);
        }
    }

    const bool f32o = is_final && f32;
    bf16*  Cb = (bf16*)Cv;
    float* Cf = (float*)Cv;

#pragma unroll
    for (int i = 0; i < 4; ++i) {
        const int row = bm + wm * 64 + i * 16 + g * 4;
#pragma unroll
        for (int j = 0; j < JF; ++j) {
            const int col = bn + wn * (JF * 16) + j * 16 + c;
            const float bv = f32 ? ((const float*)biasraw)[col]
                                 : __bfloat162float(((const bf16*)biasraw)[col]);
            const float sc = (scale_q && col < 1024) ? 0.18033688f : 1.0f;
            if (f32o) {
#pragma unroll
                for (int t = 0; t < 4; ++t)
                    Cf[(size_t)(row + t) * N + col] = (acc[i][j][t] + bv) * sc;
            } else {
#pragma unroll
                for (int t = 0; t < 4; ++t)
                    Cb[(size_t)(row + t) * N + col] =
                        __float2bfloat16((acc[i][j][t] + bv) * sc);
            }
        }
    }
}

// ---------------------------------------------------------------------------
// MFMA flash attention v9: round-4's schedule (heavy/light pairing + bh->XCD
// locality, FETCH-verified) widened to 8 waves x 16 queries per 128-q block
// (512 threads). Same LDS/tile/staging volume; 2 blocks/CU -> 16 waves/CU
// while pairs alive, 8 waves/CU solo-heavy (2x round-4 at every phase).
// Staging role-split: waves 0-3 stage K (async), waves 4-7 stage V.
// ---------------------------------------------------------------------------
__global__ __launch_bounds__(512) void attn_mfma(
    const bf16* __restrict__ qkv, bf16* __restrict__ y)
{
    __shared__ __bf16 Ks[2][128 * 64];   // [buf][key][dim], chunk ^ (key&7)
    __shared__ __bf16 Vt[2][64 * 128];   // [buf][dim][kappa], chunk ^ (dim&7)

    const int tid  = threadIdx.x;
    const int lane = tid & 63;
    const int w    = tid >> 6;           // 0..7
    const int c    = lane & 15;
    const int g    = lane >> 4;

    // decode: i = role*256 + ((j*4 + bh_hi)<<3 | bh_lo); XCD = i%8 = bh&7
    const int i    = blockIdx.x;
    const int role = i >> 8;             // 0 = heavy, 1 = light
    const int bhl  = i & 7;
    const int t5   = (i & 255) >> 3;     // 0..31
    const int j    = t5 >> 2;            // 0..7
    const int bh   = ((t5 & 3) << 3) | bhl;
    const int qblk = role ? j : (15 - j);
    const int bb   = bh >> 4;
    const int h    = bh & 15;
    const size_t base = (size_t)bb * T_SEQ * HD3 + (size_t)h * 64;

    // staging indices (st = index within the staging half)
    const bool kstage = (tid < 256);
    const int st   = tid & 255;
    const int krow = st >> 3;                        // K: 0..31 (+ q*32)
    const int klc  = ((st & 7) ^ (krow & 7)) * 8;    // K: logical dim col
    const int kq   = st & 31;                        // V: key group
    const int dgv  = st >> 5;                        // V: dim group 0..7
    const int vchunk = (kq >> 3) * 4 + (kq & 3);
    const int vlow   = ((kq >> 2) & 1) * 4;

    const bf16* kgbase = qkv + base + 1024;
    const bf16* vgbase = qkv + base + 2048;

    bf16x8 ones;
#pragma unroll
    for (int ii = 0; ii < 8; ++ii) ones[ii] = (__bf16)1.0f;

    const int q0 = qblk * 128;
    const int qw = q0 + w * 16;          // wave query origin (16 q per wave)

    // Q B-fragment (pre-scaled by 0.125*log2e in gemm1 epilogue)
    bf16x8 qf[2];
#pragma unroll
    for (int kf2 = 0; kf2 < 2; ++kf2)
        qf[kf2] = *(const bf16x8*)(qkv + base
            + (size_t)(qw + c) * HD3 + kf2 * 32 + g * 8);

    float4v o[4] = {};
    float4v ol = {};                     // lsum via ones-MFMA

    // ---- prologue: stage tile 0 into buf 0 ----
    if (kstage) {
#pragma unroll
        for (int q = 0; q < 4; ++q)
            async_copy16(kgbase + (size_t)(q * 32 + krow) * HD3 + klc,
                         &Ks[0][q * 2048 + st * 8]);
    } else {
        bf16x8 vr[4];
#pragma unroll
        for (int r = 0; r < 4; ++r)
            vr[r] = *(const bf16x8*)(vgbase + (size_t)(kq * 4 + r) * HD3 + dgv * 8);
#pragma unroll
        for (int jj = 0; jj < 8; ++jj) {
            const int d = dgv * 8 + jj;
            bf16x4v pk;
#pragma unroll
            for (int r = 0; r < 4; ++r) pk[r] = vr[r][jj];
            *(bf16x4v*)&Vt[0][d * 128 + ((vchunk ^ (d & 7)) << 3) + vlow] = pk;
        }
    }
    __syncthreads();

    int b = 0;
    for (int kt = 0; kt <= q0; kt += 128, b ^= 1) {
        const bool more = (kt + 128 <= q0);
        bf16x8 vr[4];
        if (more) {
            if (kstage) {
#pragma unroll
                for (int q = 0; q < 4; ++q)
                    async_copy16(kgbase + (size_t)(kt + 128 + q * 32 + krow) * HD3 + klc,
                                 &Ks[b ^ 1][q * 2048 + st * 8]);
            } else {
#pragma unroll
                for (int r = 0; r < 4; ++r)
                    vr[r] = *(const bf16x8*)(vgbase + (size_t)(kt + 128 + kq * 4 + r) * HD3 + dgv * 8);
            }
        }

#pragma unroll
        for (int hf = 0; hf < 2; ++hf) {
            if (kt + hf * 64 > qw + 15) continue;   // whole half masked for wave

            // ---- S^T = K Q^T over 64 keys x 16 queries ----
            float4v sacc[4] = {};
            __builtin_amdgcn_s_setprio(1);
#pragma unroll
            for (int jb = 0; jb < 4; ++jb) {
                const int key = hf * 64 + jb * 16 + c;
                bf16x8 a0 = *(const bf16x8*)&Ks[b][key * 64 + ((g ^ (c & 7)) * 8)];
                bf16x8 a1 = *(const bf16x8*)&Ks[b][key * 64 + (((4 + g) ^ (c & 7)) * 8)];
                sacc[jb] = MFMA16x16x32(a0, qf[0], sacc[jb]);
                sacc[jb] = MFMA16x16x32(a1, qf[1], sacc[jb]);
            }
            __builtin_amdgcn_s_setprio(0);

            // ---- mask + exp2 + pack P (registers only) ----
            bf16x8 pf[2];
            {
                if (kt + hf * 64 + 63 > qw) {
                    const int query = qw + c;
#pragma unroll
                    for (int jb = 0; jb < 4; ++jb) {
                        const int kb = kt + hf * 64 + jb * 16 + g * 4;
#pragma unroll
                        for (int t = 0; t < 4; ++t)
                            if (kb + t > query) sacc[jb][t] = -1e30f;
                    }
                }
#pragma unroll
                for (int jb = 0; jb < 4; ++jb)
#pragma unroll
                    for (int t = 0; t < 4; ++t)
                        sacc[jb][t] = EXP2F(sacc[jb][t]);
#pragma unroll
                for (int lkf = 0; lkf < 2; ++lkf) {
                    bf16x8 pk;
#pragma unroll
                    for (int jj = 0; jj < 8; ++jj)
                        pk[jj] = (__bf16)sacc[lkf * 2 + (jj >> 2)][jj & 3];
                    pf[lkf] = pk;
                }
            }

            // ---- O^T += V^T P ; lsum += 1^T P (this half) ----
            __builtin_amdgcn_s_setprio(1);
#pragma unroll
            for (int lkf = 0; lkf < 2; ++lkf) {
                const int kf = hf * 2 + lkf;
                ol = MFMA16x16x32(ones, pf[lkf], ol);
#pragma unroll
                for (int dn = 0; dn < 4; ++dn) {
                    const int d = dn * 16 + c;
                    bf16x8 vf = *(const bf16x8*)
                        &Vt[b][d * 128 + (((kf * 4 + g) ^ (d & 7)) << 3)];
                    o[dn] = MFMA16x16x32(vf, pf[lkf], o[dn]);
                }
            }
            __builtin_amdgcn_s_setprio(0);
        }

        if (more && !kstage) {
#pragma unroll
            for (int jj = 0; jj < 8; ++jj) {
                const int d = dgv * 8 + jj;
                bf16x4v pk;
#pragma unroll
                for (int r = 0; r < 4; ++r) pk[r] = vr[r][jj];
                *(bf16x4v*)&Vt[b ^ 1][d * 128 + ((vchunk ^ (d & 7)) << 3) + vlow] = pk;
            }
        }
        __syncthreads();
    }

    // ---- store: lane holds query q (col c), dims dn*16+g*4+t ----
    {
        const float linv = 1.f / ol.x;
        const int q = qw + c;
        const size_t yb = ((size_t)bb * T_SEQ + q) * CDIM + h * 64;
#pragma unroll
        for (int dn = 0; dn < 4; ++dn) {
            bf16x4v ov;
#pragma unroll
            for (int t = 0; t < 4; ++t)
                ov[t] = (__bf16)(o[dn][t] * linv);
            *(bf16x4v*)&y[yb + dn * 16 + g * 4] = ov;
        }
    }
}

// ---------------------------------------------------------------------------
extern "C" void kernel_launch(void* const* d_in, const int* in_sizes, int n_in,
                              void* d_out, int out_size, void* d_ws, size_t ws_size,
                              hipStream_t stream)
{
    const int M = 4096;   // B*T
    char* ws = (char*)d_ws;

    // Footprint identical to the proven baseline: max offset 50,331,904 B.
    int*  flag = (int*)ws;                        // 256 B
    bf16* xb   = (bf16*)(ws + 256);               // 8 MB
    bf16* wab  = (bf16*)(ws + 8388864);           // 6 MB
    bf16* wpb  = (bf16*)(ws + 14680320);          // 2 MB
    bf16* qkv  = (bf16*)(ws + 16777472);          // 25.2 MB
    bf16* yb   = (bf16*)(ws + 41943296);          // 8 MB -> end 50,331,904

    detect_dtype_kernel<<<1, 256, 0, stream>>>((const unsigned short*)d_in[0], flag);

    convert_f32_kernel<<<512, 256, 0, stream>>>(
        (const float*)d_in[0], (const float*)d_in[1], (const float*)d_in[3],
        xb, wab, wpb, flag);

    {   // qkv = x @ w_attn^T + b_attn (q pre-scaled); BN=128, XCD-swizzled
        dim3 grid(M / 128, 3072 / 128);   // 768 blocks, %8==0
        gemm_nt_lds_t<4><<<grid, 256, 0, stream>>>(d_in[0], xb, d_in[1], wab,
                                                   d_in[2], qkv, M, 3072, 1024,
                                                   flag, 0, 1, 1);
    }
    {   // flash attention: 8-wave blocks, pairing + bh-XCD locality
        attn_mfma<<<512, 512, 0, stream>>>(qkv, yb);
    }
    {   // out = y @ w_proj^T + b_proj; BN=64 (2 blocks/CU), XCD-swizzled
        dim3 grid(M / 128, 1024 / 64);    // 512 blocks, %8==0
        gemm_nt_lds_t<2><<<grid, 256, 0, stream>>>(yb, yb, d_in[3], wpb,
                                                   d_in[4], d_out, M, 1024, 1024,
                                                   flag, 1, 0, 1);
    }
    (void)in_sizes; (void)n_in; (void)out_size; (void)ws_size;
}

// Round 7
// 198.021 us; speedup vs baseline: 1.2963x; 1.0068x over previous
//
#include <hip/hip_runtime.h>
#include <hip/hip_bf16.h>

using bf16 = __hip_bfloat16;

typedef __bf16 bf16x8 __attribute__((ext_vector_type(8)));
typedef __bf16 bf16x4v __attribute__((ext_vector_type(4)));
typedef float  float4v __attribute__((ext_vector_type(4)));

#define MFMA16x16x32(a, b, c) __builtin_amdgcn_mfma_f32_16x16x32_bf16((a), (b), (c), 0, 0, 0)

#if __has_builtin(__builtin_amdgcn_exp2f)
#define EXP2F(x) __builtin_amdgcn_exp2f(x)
#else
#define EXP2F(x) exp2f(x)
#endif

#define T_SEQ 2048
#define NHEAD 16
#define CDIM  1024
#define HD3   3072

// async global->LDS, 16B per lane. LDS dest must be wave-uniform base + lane*16.
__device__ __forceinline__ void async_copy16(const void* g, void* l) {
    __builtin_amdgcn_global_load_lds(
        (__attribute__((address_space(1))) unsigned int*)g,
        (__attribute__((address_space(3))) unsigned int*)l,
        16, 0, 0);
}

// ---------------------------------------------------------------------------
// Convert + self-contained dtype detection (bisect: this fusion is kept from
// round 6; attn is reverted to the round-5 proven kernel). Each block
// re-detects over the first 16384 u16 of x (L2-hit after block 0); block 0
// publishes flag[0] for the GEMMs. flag=1 -> fp32 inputs.
// ---------------------------------------------------------------------------
__global__ __launch_bounds__(256) void convert_detect_kernel(
    const float* __restrict__ x, const float* __restrict__ wa,
    const float* __restrict__ wp,
    bf16* __restrict__ xb, bf16* __restrict__ wab, bf16* __restrict__ wpb,
    int* __restrict__ flag)
{
    __shared__ int red[256];
    const unsigned short* xs = (const unsigned short*)x;
    int cnt = 0;
    for (int i = threadIdx.x; i < 16384; i += 256) {
        const unsigned short u = xs[i];
        const int e = (u >> 7) & 0xFF;
        if (e == 0xFF || (e != 0 && e < 0x60)) cnt++;
    }
    red[threadIdx.x] = cnt;
    __syncthreads();
    for (int s = 128; s > 0; s >>= 1) {
        if (threadIdx.x < s) red[threadIdx.x] += red[threadIdx.x + s];
        __syncthreads();
    }
    const int isf32 = (red[0] > 100) ? 1 : 0;
    if (blockIdx.x == 0 && threadIdx.x == 0) flag[0] = isf32;
    if (!isf32) return;

    const int stride = gridDim.x * 256;
    for (int i = blockIdx.x * 256 + threadIdx.x; i < 8388608; i += stride) {
        if (i < 4194304)      xb[i] = __float2bfloat16(x[i]);
        else if (i < 7340032) wab[i - 4194304] = __float2bfloat16(wa[i - 4194304]);
        else                  wpb[i - 7340032] = __float2bfloat16(wp[i - 7340032]);
    }
}

// ---------------------------------------------------------------------------
// NT GEMM, BK=64, XOR-swizzled async staging. C[m,n]=sum_k A[m,k]B[n,k]+bias.
// JF = per-wave N fragments: JF=4 -> BN=128 (proven gemm1 path),
// JF=2 -> BN=64 (harness-verified; 2 blocks/CU for gemm2).
// swz: bijective XCD remap (requires gridDim.x*gridDim.y % 8 == 0).
// scale_q: multiply (acc+bias) by 0.125*log2e for cols < 1024 (q-columns).
// ---------------------------------------------------------------------------
template<int JF>
__global__ __launch_bounds__(256) void gemm_nt_lds_t(
    const void* __restrict__ Araw, const bf16* __restrict__ Aconv,
    const void* __restrict__ Braw, const bf16* __restrict__ Bconv,
    const void* __restrict__ biasraw, void* __restrict__ Cv,
    int M, int N, int K, const int* __restrict__ flag, int is_final,
    int scale_q, int swz)
{
    const bool f32 = (flag[0] != 0);
    const bf16* A = f32 ? Aconv : (const bf16*)Araw;
    const bf16* B = f32 ? Bconv : (const bf16*)Braw;

    __shared__ bf16 As[128 * 64];
    __shared__ bf16 Bs[JF * 32 * 64];

    const int tid  = threadIdx.x;
    const int lane = tid & 63;
    const int wave = tid >> 6;
    const int wm = wave & 1, wn = wave >> 1;
    const int c = lane & 15, g = lane >> 4;

    int bx = blockIdx.x, by = blockIdx.y;
    if (swz) {
        const int nwg = gridDim.x * gridDim.y;
        const int lin = by * gridDim.x + bx;
        const int nl  = (lin & 7) * (nwg >> 3) + (lin >> 3);
        bx = nl % gridDim.x;
        by = nl / gridDim.x;
    }
    const int bm = bx * 128;
    const int bn = by * (JF * 32);

    const int srow = tid >> 3;
    const int slc  = ((tid & 7) ^ (srow & 7)) * 8;
    const bf16* gA = A + (size_t)(bm + srow) * K + slc;
    const bf16* gB = B + (size_t)(bn + srow) * K + slc;

    float4v acc[4][JF] = {};

    for (int k0 = 0; k0 < K; k0 += 64) {
        __syncthreads();
#pragma unroll
        for (int q = 0; q < 4; ++q)
            async_copy16(gA + k0 + (size_t)(q * 32) * K, As + q * 2048 + tid * 8);
#pragma unroll
        for (int q = 0; q < JF; ++q)
            async_copy16(gB + k0 + (size_t)(q * 32) * K, Bs + q * 2048 + tid * 8);
        __syncthreads();

#pragma unroll
        for (int kk = 0; kk < 2; ++kk) {
            bf16x8 af[4], bfr[JF];
#pragma unroll
            for (int i = 0; i < 4; ++i)
                af[i]  = *(const bf16x8*)&As[(wm * 64 + i * 16 + c) * 64 +
                                             (((kk * 4 + g) ^ (c & 7)) * 8)];
#pragma unroll
            for (int j = 0; j < JF; ++j)
                bfr[j] = *(const bf16x8*)&Bs[(wn * (JF * 16) + j * 16 + c) * 64 +
                                             (((kk * 4 + g) ^ (c & 7)) * 8)];
#pragma unroll
            for (int i = 0; i < 4; ++i)
#pragma unroll
                for (int j = 0; j < JF; ++j)
                    acc[i][j] = MFMA16x16x32(af[i], bfr[j], acc[i][j]);
        }
    }

    const bool f32o = is_final && f32;
    bf16*  Cb = (bf16*)Cv;
    float* Cf = (float*)Cv;

#pragma unroll
    for (int i = 0; i < 4; ++i) {
        const int row = bm + wm * 64 + i * 16 + g * 4;
#pragma unroll
        for (int j = 0; j < JF; ++j) {
            const int col = bn + wn * (JF * 16) + j * 16 + c;
            const float bv = f32 ? ((const float*)biasraw)[col]
                                 : __bfloat162float(((const bf16*)biasraw)[col]);
            const float sc = (scale_q && col < 1024) ? 0.18033688f : 1.0f;
            if (f32o) {
#pragma unroll
                for (int t = 0; t < 4; ++t)
                    Cf[(size_t)(row + t) * N + col] = (acc[i][j][t] + bv) * sc;
            } else {
#pragma unroll
                for (int t = 0; t < 4; ++t)
                    Cb[(size_t)(row + t) * N + col] =
                        __float2bfloat16((acc[i][j][t] + bv) * sc);
            }
        }
    }
}

// ---------------------------------------------------------------------------
// MFMA flash attention v9 (round-5 proven, reverted verbatim): heavy/light
// pairing + bh->XCD locality, 8 waves x 16 queries per 128-q block (512
// threads). Staging role-split: waves 0-3 stage K (async), waves 4-7 stage V.
// ---------------------------------------------------------------------------
__global__ __launch_bounds__(512) void attn_mfma(
    const bf16* __restrict__ qkv, bf16* __restrict__ y)
{
    __shared__ __bf16 Ks[2][128 * 64];   // [buf][key][dim], chunk ^ (key&7)
    __shared__ __bf16 Vt[2][64 * 128];   // [buf][dim][kappa], chunk ^ (dim&7)

    const int tid  = threadIdx.x;
    const int lane = tid & 63;
    const int w    = tid >> 6;           // 0..7
    const int c    = lane & 15;
    const int g    = lane >> 4;

    // decode: i = role*256 + ((j*4 + bh_hi)<<3 | bh_lo); XCD = i%8 = bh&7
    const int i    = blockIdx.x;
    const int role = i >> 8;             // 0 = heavy, 1 = light
    const int bhl  = i & 7;
    const int t5   = (i & 255) >> 3;     // 0..31
    const int j    = t5 >> 2;            // 0..7
    const int bh   = ((t5 & 3) << 3) | bhl;
    const int qblk = role ? j : (15 - j);
    const int bb   = bh >> 4;
    const int h    = bh & 15;
    const size_t base = (size_t)bb * T_SEQ * HD3 + (size_t)h * 64;

    // staging indices (st = index within the staging half)
    const bool kstage = (tid < 256);
    const int st   = tid & 255;
    const int krow = st >> 3;                        // K: 0..31 (+ q*32)
    const int klc  = ((st & 7) ^ (krow & 7)) * 8;    // K: logical dim col
    const int kq   = st & 31;                        // V: key group
    const int dgv  = st >> 5;                        // V: dim group 0..7
    const int vchunk = (kq >> 3) * 4 + (kq & 3);
    const int vlow   = ((kq >> 2) & 1) * 4;

    const bf16* kgbase = qkv + base + 1024;
    const bf16* vgbase = qkv + base + 2048;

    bf16x8 ones;
#pragma unroll
    for (int ii = 0; ii < 8; ++ii) ones[ii] = (__bf16)1.0f;

    const int q0 = qblk * 128;
    const int qw = q0 + w * 16;          // wave query origin (16 q per wave)

    // Q B-fragment (pre-scaled by 0.125*log2e in gemm1 epilogue)
    bf16x8 qf[2];
#pragma unroll
    for (int kf2 = 0; kf2 < 2; ++kf2)
        qf[kf2] = *(const bf16x8*)(qkv + base
            + (size_t)(qw + c) * HD3 + kf2 * 32 + g * 8);

    float4v o[4] = {};
    float4v ol = {};                     // lsum via ones-MFMA

    // ---- prologue: stage tile 0 into buf 0 ----
    if (kstage) {
#pragma unroll
        for (int q = 0; q < 4; ++q)
            async_copy16(kgbase + (size_t)(q * 32 + krow) * HD3 + klc,
                         &Ks[0][q * 2048 + st * 8]);
    } else {
        bf16x8 vr[4];
#pragma unroll
        for (int r = 0; r < 4; ++r)
            vr[r] = *(const bf16x8*)(vgbase + (size_t)(kq * 4 + r) * HD3 + dgv * 8);
#pragma unroll
        for (int jj = 0; jj < 8; ++jj) {
            const int d = dgv * 8 + jj;
            bf16x4v pk;
#pragma unroll
            for (int r = 0; r < 4; ++r) pk[r] = vr[r][jj];
            *(bf16x4v*)&Vt[0][d * 128 + ((vchunk ^ (d & 7)) << 3) + vlow] = pk;
        }
    }
    __syncthreads();

    int b = 0;
    for (int kt = 0; kt <= q0; kt += 128, b ^= 1) {
        const bool more = (kt + 128 <= q0);
        bf16x8 vr[4];
        if (more) {
            if (kstage) {
#pragma unroll
                for (int q = 0; q < 4; ++q)
                    async_copy16(kgbase + (size_t)(kt + 128 + q * 32 + krow) * HD3 + klc,
                                 &Ks[b ^ 1][q * 2048 + st * 8]);
            } else {
#pragma unroll
                for (int r = 0; r < 4; ++r)
                    vr[r] = *(const bf16x8*)(vgbase + (size_t)(kt + 128 + kq * 4 + r) * HD3 + dgv * 8);
            }
        }

#pragma unroll
        for (int hf = 0; hf < 2; ++hf) {
            if (kt + hf * 64 > qw + 15) continue;   // whole half masked for wave

            // ---- S^T = K Q^T over 64 keys x 16 queries ----
            float4v sacc[4] = {};
            __builtin_amdgcn_s_setprio(1);
#pragma unroll
            for (int jb = 0; jb < 4; ++jb) {
                const int key = hf * 64 + jb * 16 + c;
                bf16x8 a0 = *(const bf16x8*)&Ks[b][key * 64 + ((g ^ (c & 7)) * 8)];
                bf16x8 a1 = *(const bf16x8*)&Ks[b][key * 64 + (((4 + g) ^ (c & 7)) * 8)];
                sacc[jb] = MFMA16x16x32(a0, qf[0], sacc[jb]);
                sacc[jb] = MFMA16x16x32(a1, qf[1], sacc[jb]);
            }
            __builtin_amdgcn_s_setprio(0);

            // ---- mask + exp2 + pack P (registers only) ----
            bf16x8 pf[2];
            {
                if (kt + hf * 64 + 63 > qw) {
                    const int query = qw + c;
#pragma unroll
                    for (int jb = 0; jb < 4; ++jb) {
                        const int kb = kt + hf * 64 + jb * 16 + g * 4;
#pragma unroll
                        for (int t = 0; t < 4; ++t)
                            if (kb + t > query) sacc[jb][t] = -1e30f;
                    }
                }
#pragma unroll
                for (int jb = 0; jb < 4; ++jb)
#pragma unroll
                    for (int t = 0; t < 4; ++t)
                        sacc[jb][t] = EXP2F(sacc[jb][t]);
#pragma unroll
                for (int lkf = 0; lkf < 2; ++lkf) {
                    bf16x8 pk;
#pragma unroll
                    for (int jj = 0; jj < 8; ++jj)
                        pk[jj] = (__bf16)sacc[lkf * 2 + (jj >> 2)][jj & 3];
                    pf[lkf] = pk;
                }
            }

            // ---- O^T += V^T P ; lsum += 1^T P (this half) ----
            __builtin_amdgcn_s_setprio(1);
#pragma unroll
            for (int lkf = 0; lkf < 2; ++lkf) {
                const int kf = hf * 2 + lkf;
                ol = MFMA16x16x32(ones, pf[lkf], ol);
#pragma unroll
                for (int dn = 0; dn < 4; ++dn) {
                    const int d = dn * 16 + c;
                    bf16x8 vf = *(const bf16x8*)
                        &Vt[b][d * 128 + (((kf * 4 + g) ^ (d & 7)) << 3)];
                    o[dn] = MFMA16x16x32(vf, pf[lkf], o[dn]);
                }
            }
            __builtin_amdgcn_s_setprio(0);
        }

        if (more && !kstage) {
#pragma unroll
            for (int jj = 0; jj < 8; ++jj) {
                const int d = dgv * 8 + jj;
                bf16x4v pk;
#pragma unroll
                for (int r = 0; r < 4; ++r) pk[r] = vr[r][jj];
                *(bf16x4v*)&Vt[b ^ 1][d * 128 + ((vchunk ^ (d & 7)) << 3) + vlow] = pk;
            }
        }
        __syncthreads();
    }

    // ---- store: lane holds query q (col c), dims dn*16+g*4+t ----
    {
        const float linv = 1.f / ol.x;
        const int q = qw + c;
        const size_t yb = ((size_t)bb * T_SEQ + q) * CDIM + h * 64;
#pragma unroll
        for (int dn = 0; dn < 4; ++dn) {
            bf16x4v ov;
#pragma unroll
            for (int t = 0; t < 4; ++t)
                ov[t] = (__bf16)(o[dn][t] * linv);
            *(bf16x4v*)&y[yb + dn * 16 + g * 4] = ov;
        }
    }
}

// ---------------------------------------------------------------------------
extern "C" void kernel_launch(void* const* d_in, const int* in_sizes, int n_in,
                              void* d_out, int out_size, void* d_ws, size_t ws_size,
                              hipStream_t stream)
{
    const int M = 4096;   // B*T
    char* ws = (char*)d_ws;

    // Footprint identical to the proven baseline: max offset 50,331,904 B.
    int*  flag = (int*)ws;                        // 256 B
    bf16* xb   = (bf16*)(ws + 256);               // 8 MB
    bf16* wab  = (bf16*)(ws + 8388864);           // 6 MB
    bf16* wpb  = (bf16*)(ws + 14680320);          // 2 MB
    bf16* qkv  = (bf16*)(ws + 16777472);          // 25.2 MB
    bf16* yb   = (bf16*)(ws + 41943296);          // 8 MB -> end 50,331,904

    // convert + dtype detection fused (bisect: kept from round 6)
    convert_detect_kernel<<<512, 256, 0, stream>>>(
        (const float*)d_in[0], (const float*)d_in[1], (const float*)d_in[3],
        xb, wab, wpb, flag);

    {   // qkv = x @ w_attn^T + b_attn (q pre-scaled); BN=128, XCD-swizzled
        dim3 grid(M / 128, 3072 / 128);   // 768 blocks, %8==0
        gemm_nt_lds_t<4><<<grid, 256, 0, stream>>>(d_in[0], xb, d_in[1], wab,
                                                   d_in[2], qkv, M, 3072, 1024,
                                                   flag, 0, 1, 1);
    }
    {   // flash attention: round-5 proven kernel (8-wave, pairing, XCD)
        attn_mfma<<<512, 512, 0, stream>>>(qkv, yb);
    }
    {   // out = y @ w_proj^T + b_proj; BN=64 (2 blocks/CU), XCD-swizzled
        dim3 grid(M / 128, 1024 / 64);    // 512 blocks, %8==0
        gemm_nt_lds_t<2><<<grid, 256, 0, stream>>>(yb, yb, d_in[3], wpb,
                                                   d_in[4], d_out, M, 1024, 1024,
                                                   flag, 1, 0, 1);
    }
    (void)in_sizes; (void)n_in; (void)out_size; (void)ws_size;
}

// Round 8
// 174.648 us; speedup vs baseline: 1.4698x; 1.1338x over previous
//
#include <hip/hip_runtime.h>
#include <hip/hip_bf16.h>

using bf16 = __hip_bfloat16;

typedef __bf16 bf16x8 __attribute__((ext_vector_type(8)));
typedef __bf16 bf16x4v __attribute__((ext_vector_type(4)));
typedef float  float4v __attribute__((ext_vector_type(4)));
typedef unsigned short u16x8 __attribute__((ext_vector_type(8)));

#define MFMA16x16x32(a, b, c) __builtin_amdgcn_mfma_f32_16x16x32_bf16((a), (b), (c), 0, 0, 0)

#if __has_builtin(__builtin_amdgcn_exp2f)
#define EXP2F(x) __builtin_amdgcn_exp2f(x)
#else
#define EXP2F(x) exp2f(x)
#endif

#define T_SEQ 2048
#define NHEAD 16
#define CDIM  1024
#define HD3   3072

// async global->LDS, 16B per lane. LDS dest must be wave-uniform base + lane*16.
__device__ __forceinline__ void async_copy16(const void* g, void* l) {
    __builtin_amdgcn_global_load_lds(
        (__attribute__((address_space(1))) unsigned int*)g,
        (__attribute__((address_space(3))) unsigned int*)l,
        16, 0, 0);
}

// ---------------------------------------------------------------------------
// Convert + dtype detection, VECTORIZED (G13): float4 loads + bf16x4 stores,
// three branch-free per-region loops. Detection scans the same 16384 u16 of x
// via ushort8 loads (identical count & threshold -> identical flag). Each
// block re-detects (L2-hit); block 0 publishes flag[0]. flag=1 -> fp32 input.
// ---------------------------------------------------------------------------
__global__ __launch_bounds__(256) void convert_detect_kernel(
    const float* __restrict__ x, const float* __restrict__ wa,
    const float* __restrict__ wp,
    bf16* __restrict__ xb, bf16* __restrict__ wab, bf16* __restrict__ wpb,
    int* __restrict__ flag)
{
    __shared__ int red[256];
    const u16x8* xs8 = (const u16x8*)x;
    int cnt = 0;
    for (int i = threadIdx.x; i < 2048; i += 256) {
        const u16x8 v = xs8[i];
#pragma unroll
        for (int t = 0; t < 8; ++t) {
            const int e = (v[t] >> 7) & 0xFF;
            if (e == 0xFF || (e != 0 && e < 0x60)) cnt++;
        }
    }
    red[threadIdx.x] = cnt;
    __syncthreads();
    for (int s = 128; s > 0; s >>= 1) {
        if (threadIdx.x < s) red[threadIdx.x] += red[threadIdx.x + s];
        __syncthreads();
    }
    const int isf32 = (red[0] > 100) ? 1 : 0;
    if (blockIdx.x == 0 && threadIdx.x == 0) flag[0] = isf32;
    if (!isf32) return;

    const int gid    = blockIdx.x * 256 + threadIdx.x;
    const int stride = gridDim.x * 256;
    const float4v* x4  = (const float4v*)x;    // 1048576 float4
    const float4v* wa4 = (const float4v*)wa;   //  786432 float4
    const float4v* wp4 = (const float4v*)wp;   //  262144 float4
    bf16x4v* xb4  = (bf16x4v*)xb;
    bf16x4v* wab4 = (bf16x4v*)wab;
    bf16x4v* wpb4 = (bf16x4v*)wpb;

    for (int i = gid; i < 1048576; i += stride) {
        const float4v v = x4[i];
        bf16x4v o;
#pragma unroll
        for (int t = 0; t < 4; ++t) o[t] = (__bf16)v[t];
        xb4[i] = o;
    }
    for (int i = gid; i < 786432; i += stride) {
        const float4v v = wa4[i];
        bf16x4v o;
#pragma unroll
        for (int t = 0; t < 4; ++t) o[t] = (__bf16)v[t];
        wab4[i] = o;
    }
    for (int i = gid; i < 262144; i += stride) {
        const float4v v = wp4[i];
        bf16x4v o;
#pragma unroll
        for (int t = 0; t < 4; ++t) o[t] = (__bf16)v[t];
        wpb4[i] = o;
    }
}

// ---------------------------------------------------------------------------
// NT GEMM, BK=64, XOR-swizzled async staging. C[m,n]=sum_k A[m,k]B[n,k]+bias.
// JF = per-wave N fragments: JF=4 -> BN=128 (proven gemm1 path),
// JF=2 -> BN=64 (harness-verified; 2 blocks/CU for gemm2).
// swz: bijective XCD remap (requires gridDim.x*gridDim.y % 8 == 0).
// scale_q: multiply (acc+bias) by 0.125*log2e for cols < 1024 (q-columns).
// ---------------------------------------------------------------------------
template<int JF>
__global__ __launch_bounds__(256) void gemm_nt_lds_t(
    const void* __restrict__ Araw, const bf16* __restrict__ Aconv,
    const void* __restrict__ Braw, const bf16* __restrict__ Bconv,
    const void* __restrict__ biasraw, void* __restrict__ Cv,
    int M, int N, int K, const int* __restrict__ flag, int is_final,
    int scale_q, int swz)
{
    const bool f32 = (flag[0] != 0);
    const bf16* A = f32 ? Aconv : (const bf16*)Araw;
    const bf16* B = f32 ? Bconv : (const bf16*)Braw;

    __shared__ bf16 As[128 * 64];
    __shared__ bf16 Bs[JF * 32 * 64];

    const int tid  = threadIdx.x;
    const int lane = tid & 63;
    const int wave = tid >> 6;
    const int wm = wave & 1, wn = wave >> 1;
    const int c = lane & 15, g = lane >> 4;

    int bx = blockIdx.x, by = blockIdx.y;
    if (swz) {
        const int nwg = gridDim.x * gridDim.y;
        const int lin = by * gridDim.x + bx;
        const int nl  = (lin & 7) * (nwg >> 3) + (lin >> 3);
        bx = nl % gridDim.x;
        by = nl / gridDim.x;
    }
    const int bm = bx * 128;
    const int bn = by * (JF * 32);

    const int srow = tid >> 3;
    const int slc  = ((tid & 7) ^ (srow & 7)) * 8;
    const bf16* gA = A + (size_t)(bm + srow) * K + slc;
    const bf16* gB = B + (size_t)(bn + srow) * K + slc;

    float4v acc[4][JF] = {};

    for (int k0 = 0; k0 < K; k0 += 64) {
        __syncthreads();
#pragma unroll
        for (int q = 0; q < 4; ++q)
            async_copy16(gA + k0 + (size_t)(q * 32) * K, As + q * 2048 + tid * 8);
#pragma unroll
        for (int q = 0; q < JF; ++q)
            async_copy16(gB + k0 + (size_t)(q * 32) * K, Bs + q * 2048 + tid * 8);
        __syncthreads();

#pragma unroll
        for (int kk = 0; kk < 2; ++kk) {
            bf16x8 af[4], bfr[JF];
#pragma unroll
            for (int i = 0; i < 4; ++i)
                af[i]  = *(const bf16x8*)&As[(wm * 64 + i * 16 + c) * 64 +
                                             (((kk * 4 + g) ^ (c & 7)) * 8)];
#pragma unroll
            for (int j = 0; j < JF; ++j)
                bfr[j] = *(const bf16x8*)&Bs[(wn * (JF * 16) + j * 16 + c) * 64 +
                                             (((kk * 4 + g) ^ (c & 7)) * 8)];
#pragma unroll
            for (int i = 0; i < 4; ++i)
#pragma unroll
                for (int j = 0; j < JF; ++j)
                    acc[i][j] = MFMA16x16x32(af[i], bfr[j], acc[i][j]);
        }
    }

    const bool f32o = is_final && f32;
    bf16*  Cb = (bf16*)Cv;
    float* Cf = (float*)Cv;

#pragma unroll
    for (int i = 0; i < 4; ++i) {
        const int row = bm + wm * 64 + i * 16 + g * 4;
#pragma unroll
        for (int j = 0; j < JF; ++j) {
            const int col = bn + wn * (JF * 16) + j * 16 + c;
            const float bv = f32 ? ((const float*)biasraw)[col]
                                 : __bfloat162float(((const bf16*)biasraw)[col]);
            const float sc = (scale_q && col < 1024) ? 0.18033688f : 1.0f;
            if (f32o) {
#pragma unroll
                for (int t = 0; t < 4; ++t)
                    Cf[(size_t)(row + t) * N + col] = (acc[i][j][t] + bv) * sc;
            } else {
#pragma unroll
                for (int t = 0; t < 4; ++t)
                    Cb[(size_t)(row + t) * N + col] =
                        __float2bfloat16((acc[i][j][t] + bv) * sc);
            }
        }
    }
}

// ---------------------------------------------------------------------------
// MFMA flash attention v9 (round-5/7 proven, unchanged): heavy/light pairing
// + bh->XCD locality, 8 waves x 16 queries per 128-q block (512 threads).
// Staging role-split: waves 0-3 stage K (async), waves 4-7 stage V.
// ---------------------------------------------------------------------------
__global__ __launch_bounds__(512) void attn_mfma(
    const bf16* __restrict__ qkv, bf16* __restrict__ y)
{
    __shared__ __bf16 Ks[2][128 * 64];   // [buf][key][dim], chunk ^ (key&7)
    __shared__ __bf16 Vt[2][64 * 128];   // [buf][dim][kappa], chunk ^ (dim&7)

    const int tid  = threadIdx.x;
    const int lane = tid & 63;
    const int w    = tid >> 6;           // 0..7
    const int c    = lane & 15;
    const int g    = lane >> 4;

    // decode: i = role*256 + ((j*4 + bh_hi)<<3 | bh_lo); XCD = i%8 = bh&7
    const int i    = blockIdx.x;
    const int role = i >> 8;             // 0 = heavy, 1 = light
    const int bhl  = i & 7;
    const int t5   = (i & 255) >> 3;     // 0..31
    const int j    = t5 >> 2;            // 0..7
    const int bh   = ((t5 & 3) << 3) | bhl;
    const int qblk = role ? j : (15 - j);
    const int bb   = bh >> 4;
    const int h    = bh & 15;
    const size_t base = (size_t)bb * T_SEQ * HD3 + (size_t)h * 64;

    // staging indices (st = index within the staging half)
    const bool kstage = (tid < 256);
    const int st   = tid & 255;
    const int krow = st >> 3;                        // K: 0..31 (+ q*32)
    const int klc  = ((st & 7) ^ (krow & 7)) * 8;    // K: logical dim col
    const int kq   = st & 31;                        // V: key group
    const int dgv  = st >> 5;                        // V: dim group 0..7
    const int vchunk = (kq >> 3) * 4 + (kq & 3);
    const int vlow   = ((kq >> 2) & 1) * 4;

    const bf16* kgbase = qkv + base + 1024;
    const bf16* vgbase = qkv + base + 2048;

    bf16x8 ones;
#pragma unroll
    for (int ii = 0; ii < 8; ++ii) ones[ii] = (__bf16)1.0f;

    const int q0 = qblk * 128;
    const int qw = q0 + w * 16;          // wave query origin (16 q per wave)

    // Q B-fragment (pre-scaled by 0.125*log2e in gemm1 epilogue)
    bf16x8 qf[2];
#pragma unroll
    for (int kf2 = 0; kf2 < 2; ++kf2)
        qf[kf2] = *(const bf16x8*)(qkv + base
            + (size_t)(qw + c) * HD3 + kf2 * 32 + g * 8);

    float4v o[4] = {};
    float4v ol = {};                     // lsum via ones-MFMA

    // ---- prologue: stage tile 0 into buf 0 ----
    if (kstage) {
#pragma unroll
        for (int q = 0; q < 4; ++q)
            async_copy16(kgbase + (size_t)(q * 32 + krow) * HD3 + klc,
                         &Ks[0][q * 2048 + st * 8]);
    } else {
        bf16x8 vr[4];
#pragma unroll
        for (int r = 0; r < 4; ++r)
            vr[r] = *(const bf16x8*)(vgbase + (size_t)(kq * 4 + r) * HD3 + dgv * 8);
#pragma unroll
        for (int jj = 0; jj < 8; ++jj) {
            const int d = dgv * 8 + jj;
            bf16x4v pk;
#pragma unroll
            for (int r = 0; r < 4; ++r) pk[r] = vr[r][jj];
            *(bf16x4v*)&Vt[0][d * 128 + ((vchunk ^ (d & 7)) << 3) + vlow] = pk;
        }
    }
    __syncthreads();

    int b = 0;
    for (int kt = 0; kt <= q0; kt += 128, b ^= 1) {
        const bool more = (kt + 128 <= q0);
        bf16x8 vr[4];
        if (more) {
            if (kstage) {
#pragma unroll
                for (int q = 0; q < 4; ++q)
                    async_copy16(kgbase + (size_t)(kt + 128 + q * 32 + krow) * HD3 + klc,
                                 &Ks[b ^ 1][q * 2048 + st * 8]);
            } else {
#pragma unroll
                for (int r = 0; r < 4; ++r)
                    vr[r] = *(const bf16x8*)(vgbase + (size_t)(kt + 128 + kq * 4 + r) * HD3 + dgv * 8);
            }
        }

#pragma unroll
        for (int hf = 0; hf < 2; ++hf) {
            if (kt + hf * 64 > qw + 15) continue;   // whole half masked for wave

            // ---- S^T = K Q^T over 64 keys x 16 queries ----
            float4v sacc[4] = {};
            __builtin_amdgcn_s_setprio(1);
#pragma unroll
            for (int jb = 0; jb < 4; ++jb) {
                const int key = hf * 64 + jb * 16 + c;
                bf16x8 a0 = *(const bf16x8*)&Ks[b][key * 64 + ((g ^ (c & 7)) * 8)];
                bf16x8 a1 = *(const bf16x8*)&Ks[b][key * 64 + (((4 + g) ^ (c & 7)) * 8)];
                sacc[jb] = MFMA16x16x32(a0, qf[0], sacc[jb]);
                sacc[jb] = MFMA16x16x32(a1, qf[1], sacc[jb]);
            }
            __builtin_amdgcn_s_setprio(0);

            // ---- mask + exp2 + pack P (registers only) ----
            bf16x8 pf[2];
            {
                if (kt + hf * 64 + 63 > qw) {
                    const int query = qw + c;
#pragma unroll
                    for (int jb = 0; jb < 4; ++jb) {
                        const int kb = kt + hf * 64 + jb * 16 + g * 4;
#pragma unroll
                        for (int t = 0; t < 4; ++t)
                            if (kb + t > query) sacc[jb][t] = -1e30f;
                    }
                }
#pragma unroll
                for (int jb = 0; jb < 4; ++jb)
#pragma unroll
                    for (int t = 0; t < 4; ++t)
                        sacc[jb][t] = EXP2F(sacc[jb][t]);
#pragma unroll
                for (int lkf = 0; lkf < 2; ++lkf) {
                    bf16x8 pk;
#pragma unroll
                    for (int jj = 0; jj < 8; ++jj)
                        pk[jj] = (__bf16)sacc[lkf * 2 + (jj >> 2)][jj & 3];
                    pf[lkf] = pk;
                }
            }

            // ---- O^T += V^T P ; lsum += 1^T P (this half) ----
            __builtin_amdgcn_s_setprio(1);
#pragma unroll
            for (int lkf = 0; lkf < 2; ++lkf) {
                const int kf = hf * 2 + lkf;
                ol = MFMA16x16x32(ones, pf[lkf], ol);
#pragma unroll
                for (int dn = 0; dn < 4; ++dn) {
                    const int d = dn * 16 + c;
                    bf16x8 vf = *(const bf16x8*)
                        &Vt[b][d * 128 + (((kf * 4 + g) ^ (d & 7)) << 3)];
                    o[dn] = MFMA16x16x32(vf, pf[lkf], o[dn]);
                }
            }
            __builtin_amdgcn_s_setprio(0);
        }

        if (more && !kstage) {
#pragma unroll
            for (int jj = 0; jj < 8; ++jj) {
                const int d = dgv * 8 + jj;
                bf16x4v pk;
#pragma unroll
                for (int r = 0; r < 4; ++r) pk[r] = vr[r][jj];
                *(bf16x4v*)&Vt[b ^ 1][d * 128 + ((vchunk ^ (d & 7)) << 3) + vlow] = pk;
            }
        }
        __syncthreads();
    }

    // ---- store: lane holds query q (col c), dims dn*16+g*4+t ----
    {
        const float linv = 1.f / ol.x;
        const int q = qw + c;
        const size_t yb = ((size_t)bb * T_SEQ + q) * CDIM + h * 64;
#pragma unroll
        for (int dn = 0; dn < 4; ++dn) {
            bf16x4v ov;
#pragma unroll
            for (int t = 0; t < 4; ++t)
                ov[t] = (__bf16)(o[dn][t] * linv);
            *(bf16x4v*)&y[yb + dn * 16 + g * 4] = ov;
        }
    }
}

// ---------------------------------------------------------------------------
extern "C" void kernel_launch(void* const* d_in, const int* in_sizes, int n_in,
                              void* d_out, int out_size, void* d_ws, size_t ws_size,
                              hipStream_t stream)
{
    const int M = 4096;   // B*T
    char* ws = (char*)d_ws;

    // Footprint identical to the proven baseline: max offset 50,331,904 B.
    int*  flag = (int*)ws;                        // 256 B
    bf16* xb   = (bf16*)(ws + 256);               // 8 MB
    bf16* wab  = (bf16*)(ws + 8388864);           // 6 MB
    bf16* wpb  = (bf16*)(ws + 14680320);          // 2 MB
    bf16* qkv  = (bf16*)(ws + 16777472);          // 25.2 MB
    bf16* yb   = (bf16*)(ws + 41943296);          // 8 MB -> end 50,331,904

    // convert + dtype detection fused, vectorized (float4 -> bf16x4)
    convert_detect_kernel<<<512, 256, 0, stream>>>(
        (const float*)d_in[0], (const float*)d_in[1], (const float*)d_in[3],
        xb, wab, wpb, flag);

    {   // qkv = x @ w_attn^T + b_attn (q pre-scaled); BN=128, XCD-swizzled
        dim3 grid(M / 128, 3072 / 128);   // 768 blocks, %8==0
        gemm_nt_lds_t<4><<<grid, 256, 0, stream>>>(d_in[0], xb, d_in[1], wab,
                                                   d_in[2], qkv, M, 3072, 1024,
                                                   flag, 0, 1, 1);
    }
    {   // flash attention: round-5 proven kernel (8-wave, pairing, XCD)
        attn_mfma<<<512, 512, 0, stream>>>(qkv, yb);
    }
    {   // out = y @ w_proj^T + b_proj; BN=64 (2 blocks/CU), XCD-swizzled
        dim3 grid(M / 128, 1024 / 64);    // 512 blocks, %8==0
        gemm_nt_lds_t<2><<<grid, 256, 0, stream>>>(yb, yb, d_in[3], wpb,
                                                   d_in[4], d_out, M, 1024, 1024,
                                                   flag, 1, 0, 1);
    }
    (void)in_sizes; (void)n_in; (void)out_size; (void)ws_size;
}